// Round 3
// baseline (1249.848 us; speedup 1.0000x reference)
//
#include <hip/hip_runtime.h>
#include <math.h>

#define NEDGE 600000
#define NUSER 50000
#define NITEM 50000
#define DIMT  128
#define NIN   25000
#define NTVAL 1000

// ---------------------------------------------------------------------------
// Fused timestep-MLP LUT: for t in [0,1000): emb (numpy-rounding-exact) ->
// silu(e@W1+b1)@W2+b2 -> Tlut[t][128]. 2 t-rows per 256-thread block.
// Weights read as columns (L2-hot, 128 KB total).
// ---------------------------------------------------------------------------
__global__ __launch_bounds__(256) void lut_mlp_kernel(
        const float* __restrict__ W1, const float* __restrict__ b1,
        const float* __restrict__ W2, const float* __restrict__ b2,
        float* __restrict__ Tlut) {
    __shared__ float sE[2][128];
    __shared__ float sH[2][128];
    int r = threadIdx.x >> 7;          // 0..1
    int j = threadIdx.x & 127;         // column
    int t = blockIdx.x * 2 + r;

    // embedding element for column j
    {
        int jj = j & 63;
        const float Lf = 9.210340371976184f;   // fp32(log(10000))
        float p  = -Lf * (float)jj;
        float ae = p * 0.015625f;
        float freq = (float)exp((double)ae);
        float arg  = (float)t * freq;
        double a = (double)arg;
        sE[r][j] = (j < 64) ? (float)cos(a) : (float)sin(a);
    }
    __syncthreads();
    // h1 = silu(e @ W1 + b1)
    {
        float acc = b1[j];
        for (int k = 0; k < 128; ++k) acc = fmaf(sE[r][k], W1[k * 128 + j], acc);
        float s = 1.f / (1.f + expf(-acc));
        sH[r][j] = acc * s;
    }
    __syncthreads();
    // out = h1 @ W2 + b2
    {
        float acc = b2[j];
        for (int k = 0; k < 128; ++k) acc = fmaf(sH[r][k], W2[k * 128 + j], acc);
        Tlut[(size_t)t * 128 + j] = acc;
    }
}

// ---------------------------------------------------------------------------
// Paired fused dense:  Y = act( A@W1 [+ B@W2] + bias [+ res] )
// Two independent problems per launch. 256 threads.
// Microtile RM x 8; thread's 8 cols = {tx*4..+3, NOUT/2+tx*4..+3} so sW
// ds_read_b128 is conflict-free; sA read as b128 over k-quads.
// RESMODE: 0 none, 2 res[tidx[m]] (timestep-LUT gather).
// ---------------------------------------------------------------------------
#define ACT_NONE 0
#define ACT_RELU 1
#define ACT_SILU 2

struct DenseProb {
    const float* A; const float* W1; int K1;
    const float* B; const float* W2; int K2;
    const float* bias; const float* res; const int* tidx;
    float* Y; int M; int nblk;
};

template<int BM, int NOUT, int ACT, bool DUAL, int RESMODE>
__global__ __launch_bounds__(256, 3)
void dense3_kernel(DenseProb q0, DenseProb q1) {
    constexpr int BK = 32;
    constexpr int TX = NOUT / 8;          // 8 cols per thread
    constexpr int TY = 256 / TX;
    constexpr int RM = BM / TY;
    constexpr int NH = NOUT / 2;
    constexpr int AITER = BM / 32;        // float4s per thread staging A
    constexpr int WITER = NOUT / 32;      // float4s per thread staging W

    __shared__ float sA[BM][BK + 4];      // stride 36 floats = 144 B (16B-aligned rows)
    __shared__ float sW[BK][NOUT];

    const bool firstp = (blockIdx.x < (unsigned)q0.nblk);
    const DenseProb& q = firstp ? q0 : q1;
    const int bid = firstp ? blockIdx.x : (blockIdx.x - q0.nblk);

    const int tid = threadIdx.x;
    const int tx  = tid % TX;
    const int ty  = tid / TX;
    const int m0  = bid * BM;
    const int rowb = ty * RM;

    float acc[RM][8];
#pragma unroll
    for (int i = 0; i < RM; ++i)
#pragma unroll
        for (int j = 0; j < 8; ++j) acc[i][j] = 0.f;

    const int nkt1 = q.K1 / BK;
    const int nkt  = nkt1 + (DUAL ? q.K2 / BK : 0);

    float4 ar[AITER];
    float4 wr[WITER];

    auto issue = [&](int kt) {
        const float* X; const float* W; int K; int kk;
        if (!DUAL || kt < nkt1) { X = q.A; W = q.W1; K = q.K1; kk = kt * BK; }
        else                    { X = q.B; W = q.W2; K = q.K2; kk = (kt - nkt1) * BK; }
#pragma unroll
        for (int r = 0; r < AITER; ++r) {
            int idx = tid + r * 256;
            int row = idx >> 3, kq = idx & 7;
            int m = m0 + row;
            ar[r] = make_float4(0.f, 0.f, 0.f, 0.f);
            if (m < q.M) ar[r] = *reinterpret_cast<const float4*>(X + (size_t)m * K + kk + kq * 4);
        }
#pragma unroll
        for (int r = 0; r < WITER; ++r) {
            int idx = tid + r * 256;
            int row = idx / (NOUT / 4), nq = idx % (NOUT / 4);
            wr[r] = *reinterpret_cast<const float4*>(W + (size_t)(kk + row) * NOUT + nq * 4);
        }
    };
    auto commit = [&]() {
#pragma unroll
        for (int r = 0; r < AITER; ++r) {
            int idx = tid + r * 256;
            int row = idx >> 3, kq = idx & 7;
            *reinterpret_cast<float4*>(&sA[row][kq * 4]) = ar[r];
        }
#pragma unroll
        for (int r = 0; r < WITER; ++r) {
            int idx = tid + r * 256;
            int row = idx / (NOUT / 4), nq = idx % (NOUT / 4);
            *reinterpret_cast<float4*>(&sW[row][nq * 4]) = wr[r];
        }
    };

    issue(0);
    for (int kt = 0; kt < nkt; ++kt) {
        commit();
        __syncthreads();
        if (kt + 1 < nkt) issue(kt + 1);   // overlap next-tile global latency
#pragma unroll
        for (int qd = 0; qd < BK / 4; ++qd) {
            const int k = qd * 4;
            float w0[4][4], w1[4][4];
#pragma unroll
            for (int kk = 0; kk < 4; ++kk) {
                *reinterpret_cast<float4*>(&w0[kk][0]) = *reinterpret_cast<const float4*>(&sW[k + kk][tx * 4]);
                *reinterpret_cast<float4*>(&w1[kk][0]) = *reinterpret_cast<const float4*>(&sW[k + kk][NH + tx * 4]);
            }
#pragma unroll
            for (int i = 0; i < RM; ++i) {
                float av[4];
                *reinterpret_cast<float4*>(&av[0]) = *reinterpret_cast<const float4*>(&sA[rowb + i][k]);
#pragma unroll
                for (int kk = 0; kk < 4; ++kk) {
#pragma unroll
                    for (int j = 0; j < 4; ++j) {
                        acc[i][j]     = fmaf(av[kk], w0[kk][j], acc[i][j]);
                        acc[i][4 + j] = fmaf(av[kk], w1[kk][j], acc[i][4 + j]);
                    }
                }
            }
        }
        __syncthreads();
    }

    // epilogue
    float bb[8];
    *reinterpret_cast<float4*>(&bb[0]) = *reinterpret_cast<const float4*>(q.bias + tx * 4);
    *reinterpret_cast<float4*>(&bb[4]) = *reinterpret_cast<const float4*>(q.bias + NH + tx * 4);
#pragma unroll
    for (int i = 0; i < RM; ++i) {
        int m = m0 + rowb + i;
        if (m >= q.M) continue;
        float v[8];
#pragma unroll
        for (int j = 0; j < 8; ++j) v[j] = acc[i][j] + bb[j];
        if (RESMODE == 2) {
            int tv = q.tidx[m];
            const float* rp = q.res + (size_t)tv * NOUT;
            float4 r0 = *reinterpret_cast<const float4*>(rp + tx * 4);
            float4 r1 = *reinterpret_cast<const float4*>(rp + NH + tx * 4);
            v[0] += r0.x; v[1] += r0.y; v[2] += r0.z; v[3] += r0.w;
            v[4] += r1.x; v[5] += r1.y; v[6] += r1.z; v[7] += r1.w;
        }
#pragma unroll
        for (int j = 0; j < 8; ++j) {
            float x = v[j];
            if (ACT == ACT_RELU) x = fmaxf(x, 0.f);
            else if (ACT == ACT_SILU) { float s = 1.f / (1.f + expf(-x)); x = x * s; }
            v[j] = x;
        }
        *reinterpret_cast<float4*>(q.Y + (size_t)m * NOUT + tx * 4)      = make_float4(v[0], v[1], v[2], v[3]);
        *reinterpret_cast<float4*>(q.Y + (size_t)m * NOUT + NH + tx * 4) = make_float4(v[4], v[5], v[6], v[7]);
    }
}

// ---------------------------------------------------------------------------
// CSR build: histogram -> 3-kernel exclusive scan -> atomic bucket fill
// ---------------------------------------------------------------------------
__global__ __launch_bounds__(256) void hist_kernel(const int* __restrict__ dst,
                                                   int* __restrict__ cnt, int E) {
    int e = blockIdx.x * 256 + threadIdx.x;
    if (e < E) atomicAdd(&cnt[dst[e]], 1);
}

#define SCAN_CHUNK 2048
__global__ __launch_bounds__(256) void scan1_kernel(const int* __restrict__ cnt,
                                                    int* __restrict__ bsum, int N) {
    __shared__ int sdata[256];
    int base = blockIdx.x * SCAN_CHUNK + threadIdx.x * 8;
    int s = 0;
#pragma unroll
    for (int j = 0; j < 8; ++j) { int i = base + j; if (i < N) s += cnt[i]; }
    sdata[threadIdx.x] = s;
    __syncthreads();
    for (int st = 128; st > 0; st >>= 1) {
        if ((int)threadIdx.x < st) sdata[threadIdx.x] += sdata[threadIdx.x + st];
        __syncthreads();
    }
    if (threadIdx.x == 0) bsum[blockIdx.x] = sdata[0];
}

__global__ void scan2_kernel(int* __restrict__ bsum, int G) {
    if (threadIdx.x == 0 && blockIdx.x == 0) {
        int run = 0;
        for (int b = 0; b < G; ++b) { int v = bsum[b]; bsum[b] = run; run += v; }
    }
}

__global__ __launch_bounds__(256) void scan3_kernel(const int* __restrict__ cnt,
                                                    const int* __restrict__ bsum,
                                                    int* __restrict__ offs,
                                                    int* __restrict__ wp, int N) {
    __shared__ int sth[256];
    int t = threadIdx.x;
    int base = blockIdx.x * SCAN_CHUNK + t * 8;
    int loc[8];
    int s = 0;
#pragma unroll
    for (int j = 0; j < 8; ++j) {
        int i = base + j;
        int v = (i < N) ? cnt[i] : 0;
        loc[j] = s; s += v;
    }
    sth[t] = s;
    __syncthreads();
    for (int st = 1; st < 256; st <<= 1) {
        int v = (t >= st) ? sth[t - st] : 0;
        __syncthreads();
        sth[t] += v;
        __syncthreads();
    }
    int exc = (t == 0) ? 0 : sth[t - 1];
    int boff = bsum[blockIdx.x];
#pragma unroll
    for (int j = 0; j < 8; ++j) {
        int i = base + j;
        if (i < N) { int o = boff + exc + loc[j]; offs[i] = o; wp[i] = o; }
    }
    if (blockIdx.x == gridDim.x - 1 && t == 255) offs[N] = boff + sth[255];
}

__global__ __launch_bounds__(256) void fill_kernel(const int* __restrict__ src,
                                                   const int* __restrict__ dst,
                                                   int* __restrict__ wp,
                                                   int* __restrict__ bkt, int E) {
    int e = blockIdx.x * 256 + threadIdx.x;
    if (e < E) {
        int d = dst[e];
        int p = atomicAdd(&wp[d], 1);
        bkt[p] = src[e];
    }
}

// ---------------------------------------------------------------------------
// Paired segment-mean via CSR: one wave per dst row; lanes 0-31 edge e,
// lanes 32-63 edge e+1, float4 per lane; shfl_xor(32) combines halves.
// ---------------------------------------------------------------------------
struct GatherProb { const float* h; const int* offs; const int* bkt; float* out; int N; };

__global__ __launch_bounds__(256)
void gather2_kernel(GatherProb g0, GatherProb g1) {
    int gw = (blockIdx.x * 256 + threadIdx.x) >> 6;
    int lane = threadIdx.x & 63;
    const bool firstp = (gw < g0.N);
    const GatherProb& g = firstp ? g0 : g1;
    int row = firstp ? gw : gw - g0.N;
    if (row >= g.N) return;
    int beg = g.offs[row], end = g.offs[row + 1];
    int half = lane >> 5, c4 = lane & 31;
    const float4* __restrict__ base = reinterpret_cast<const float4*>(g.h);
    float sx = 0.f, sy = 0.f, sz = 0.f, sw = 0.f;
    for (int e = beg + half; e < end; e += 2) {
        int src = g.bkt[e];
        float4 v = base[(size_t)src * 32 + c4];
        sx += v.x; sy += v.y; sz += v.z; sw += v.w;
    }
    sx += __shfl_xor(sx, 32, 64);
    sy += __shfl_xor(sy, 32, 64);
    sz += __shfl_xor(sz, 32, 64);
    sw += __shfl_xor(sw, 32, 64);
    if (half == 0) {
        float d = (float)max(end - beg, 1);
        reinterpret_cast<float4*>(g.out)[(size_t)row * 32 + c4] =
            make_float4(sx / d, sy / d, sz / d, sw / d);
    }
}

// ---------------------------------------------------------------------------
extern "C" void kernel_launch(void* const* d_in, const int* in_sizes, int n_in,
                              void* d_out, int out_size, void* d_ws, size_t ws_size,
                              hipStream_t stream) {
    const float* x_user  = (const float*)d_in[0];
    const float* x_item  = (const float*)d_in[1];
    const int*   t_user  = (const int*)d_in[2];
    const int*   t_item  = (const int*)d_in[3];
    const int*   eui_src = (const int*)d_in[4];
    const int*   eui_dst = (const int*)d_in[5];
    const int*   eiu_src = (const int*)d_in[6];
    const int*   eiu_dst = (const int*)d_in[7];
    const float* te_W1 = (const float*)d_in[8];  const float* te_b1 = (const float*)d_in[9];
    const float* te_W2 = (const float*)d_in[10]; const float* te_b2 = (const float*)d_in[11];
    const float* proj_Wu = (const float*)d_in[12]; const float* proj_bu = (const float*)d_in[13];
    const float* proj_Wi = (const float*)d_in[14]; const float* proj_bi = (const float*)d_in[15];
    const float* sage_Wnbr  = (const float*)d_in[16];
    const float* sage_Wroot = (const float*)d_in[17];
    const float* sage_b     = (const float*)d_in[18];
    const float* mu_W1 = (const float*)d_in[19]; const float* mu_b1 = (const float*)d_in[20];
    const float* mu_W2 = (const float*)d_in[21]; const float* mu_b2 = (const float*)d_in[22];
    const float* mu_W3 = (const float*)d_in[23]; const float* mu_b3 = (const float*)d_in[24];
    const float* mi_W1 = (const float*)d_in[25]; const float* mi_b1 = (const float*)d_in[26];
    const float* mi_W2 = (const float*)d_in[27]; const float* mi_b2 = (const float*)d_in[28];
    const float* mi_W3 = (const float*)d_in[29]; const float* mi_b3 = (const float*)d_in[30];

    float* out_u = (float*)d_out;                  // [25000][64]
    float* out_i = out_u + (size_t)NIN * 64;       // [25000][32]

    // workspace: 4 big ping-pong buffers + LUT + CSR int pool
    const size_t NBIG = (size_t)NUSER * DIMT;      // 6.4M floats (25.6 MB)
    float* ws = (float*)d_ws;
    float* P0 = ws;
    float* P1 = ws + NBIG;
    float* P2 = ws + 2 * NBIG;
    float* P3 = ws + 3 * NBIG;
    float* Tlut = ws + 4 * NBIG;                   // 1000*128
    int* ip = (int*)(Tlut + NTVAL * 128);
    int* off_ui = ip;              ip += NITEM + 1;
    int* wp_ui  = ip;              ip += NITEM;
    int* cnt_ui = ip;              ip += NITEM;
    int* bkt_ui = ip;              ip += NEDGE;
    int* bsum_ui = ip;             ip += 64;
    int* off_iu = ip;              ip += NUSER + 1;
    int* wp_iu  = ip;              ip += NUSER;
    int* cnt_iu = ip;              ip += NUSER;
    int* bkt_iu = ip;              ip += NEDGE;
    int* bsum_iu = ip;             ip += 64;

    const int nb128_50k = (NUSER + 127) / 128;     // 391
    const int nb64_25k  = (NIN + 63) / 64;         // 391
    const int nb128_25k = (NIN + 127) / 128;       // 196
    const int nb256_25k = (NIN + 255) / 256;       // 98
    const int gEdges = (NEDGE + 255) / 256;
    const int gScan  = (NUSER + SCAN_CHUNK - 1) / SCAN_CHUNK;

    DenseProb qn = {};  // null slot

    // ---- timestep-MLP LUT (1000 rows, one fused kernel) ----
    lut_mlp_kernel<<<NTVAL / 2, 256, 0, stream>>>(te_W1, te_b1, te_W2, te_b2, Tlut);

    // ---- proj (merged user+item): h = x@proj_W + b + Tlut[t] ----
    {
        DenseProb qu = { x_user, proj_Wu, 64, nullptr, nullptr, 0, proj_bu, Tlut, t_user, P0, NUSER, nb128_50k };
        DenseProb qi = { x_item, proj_Wi, 32, nullptr, nullptr, 0, proj_bi, Tlut, t_item, P1, NITEM, nb128_50k };
        dense3_kernel<128, 128, ACT_NONE, false, 2><<<2 * nb128_50k, 256, 0, stream>>>(qu, qi);
    }

    // ---- CSR build (edges constant across layers) ----
    hipMemsetAsync(cnt_ui, 0, NITEM * sizeof(int), stream);
    hist_kernel<<<gEdges, 256, 0, stream>>>(eui_dst, cnt_ui, NEDGE);
    scan1_kernel<<<gScan, 256, 0, stream>>>(cnt_ui, bsum_ui, NITEM);
    scan2_kernel<<<1, 64, 0, stream>>>(bsum_ui, gScan);
    scan3_kernel<<<gScan, 256, 0, stream>>>(cnt_ui, bsum_ui, off_ui, wp_ui, NITEM);
    fill_kernel<<<gEdges, 256, 0, stream>>>(eui_src, eui_dst, wp_ui, bkt_ui, NEDGE);

    hipMemsetAsync(cnt_iu, 0, NUSER * sizeof(int), stream);
    hist_kernel<<<gEdges, 256, 0, stream>>>(eiu_dst, cnt_iu, NEDGE);
    scan1_kernel<<<gScan, 256, 0, stream>>>(cnt_iu, bsum_iu, NUSER);
    scan2_kernel<<<1, 64, 0, stream>>>(bsum_iu, gScan);
    scan3_kernel<<<gScan, 256, 0, stream>>>(cnt_iu, bsum_iu, off_iu, wp_iu, NUSER);
    fill_kernel<<<gEdges, 256, 0, stream>>>(eiu_src, eiu_dst, wp_iu, bkt_iu, NEDGE);

    // ---- SAGE layers (gather pair merged, dense pair merged) ----
    float* hu = P0; float* hi = P1; float* fa = P2; float* fb = P3;
    for (int l = 0; l < 2; ++l) {
        const float* Wn0 = sage_Wnbr  + (size_t)(l * 2 + 0) * DIMT * DIMT;
        const float* Wr0 = sage_Wroot + (size_t)(l * 2 + 0) * DIMT * DIMT;
        const float* sb0 = sage_b     + (size_t)(l * 2 + 0) * DIMT;
        const float* Wn1 = sage_Wnbr  + (size_t)(l * 2 + 1) * DIMT * DIMT;
        const float* Wr1 = sage_Wroot + (size_t)(l * 2 + 1) * DIMT * DIMT;
        const float* sb1 = sage_b     + (size_t)(l * 2 + 1) * DIMT;

        // mean_i (over e_ui of h_u) -> fa ; mean_u (over e_iu of h_i) -> fb
        {
            GatherProb gi = { hu, off_ui, bkt_ui, fa, NITEM };
            GatherProb gu = { hi, off_iu, bkt_iu, fb, NUSER };
            gather2_kernel<<<(NITEM + NUSER) * 64 / 256, 256, 0, stream>>>(gi, gu);
        }
        // new_i = relu(mean_i@Wn0 + h_i@Wr0 + b0) -> fa (alias-safe: per-block rows disjoint)
        // new_u = relu(mean_u@Wn1 + h_u@Wr1 + b1) -> fb
        {
            DenseProb qi = { fa, Wn0, DIMT, hi, Wr0, DIMT, sb0, nullptr, nullptr, fa, NITEM, nb128_50k };
            DenseProb qu = { fb, Wn1, DIMT, hu, Wr1, DIMT, sb1, nullptr, nullptr, fb, NUSER, nb128_50k };
            dense3_kernel<128, 128, ACT_RELU, true, 0><<<2 * nb128_50k, 256, 0, stream>>>(qi, qu);
        }
        float* ohu = hu; float* ohi = hi;
        hi = fa; hu = fb; fa = ohu; fb = ohi;
    }

    // ---- MLP heads (first 25000 rows; user/item merged per level) ----
    float* T0 = fa;
    float* T1 = fb;
    {
        DenseProb qu = { hu, mu_W1, 128, nullptr, nullptr, 0, mu_b1, nullptr, nullptr, T0, NIN, nb64_25k };
        DenseProb qi = { hi, mi_W1, 128, nullptr, nullptr, 0, mi_b1, nullptr, nullptr, T1, NIN, nb64_25k };
        dense3_kernel<64, 256, ACT_RELU, false, 0><<<2 * nb64_25k, 256, 0, stream>>>(qu, qi);
    }
    {
        DenseProb qu = { T0, mu_W2, 256, nullptr, nullptr, 0, mu_b2, nullptr, nullptr, T0, NIN, nb64_25k };
        DenseProb qi = { T1, mi_W2, 256, nullptr, nullptr, 0, mi_b2, nullptr, nullptr, T1, NIN, nb64_25k };
        dense3_kernel<64, 256, ACT_RELU, false, 0><<<2 * nb64_25k, 256, 0, stream>>>(qu, qi);
    }
    {
        DenseProb q = { T0, mu_W3, 256, nullptr, nullptr, 0, mu_b3, nullptr, nullptr, out_u, NIN, nb128_25k };
        dense3_kernel<128, 64, ACT_NONE, false, 0><<<nb128_25k, 256, 0, stream>>>(q, qn);
    }
    {
        DenseProb q = { T1, mi_W3, 256, nullptr, nullptr, 0, mi_b3, nullptr, nullptr, out_i, NIN, nb256_25k };
        dense3_kernel<256, 32, ACT_NONE, false, 0><<<nb256_25k, 256, 0, stream>>>(q, qn);
    }

    (void)in_sizes; (void)n_in; (void)out_size; (void)ws_size;
}

// Round 4
// 799.153 us; speedup vs baseline: 1.5640x; 1.5640x over previous
//
#include <hip/hip_runtime.h>
#include <math.h>

#define NEDGE 600000
#define NUSER 50000
#define NITEM 50000
#define DIMT  128
#define NIN   25000
#define NTVAL 1000

// ---------------------------------------------------------------------------
// Fused timestep-MLP LUT: for t in [0,1000): emb (numpy-rounding-exact) ->
// silu(e@W1+b1)@W2+b2 -> Tlut[t][128]. 2 t-rows per 256-thread block.
// ---------------------------------------------------------------------------
__global__ __launch_bounds__(256) void lut_mlp_kernel(
        const float* __restrict__ W1, const float* __restrict__ b1,
        const float* __restrict__ W2, const float* __restrict__ b2,
        float* __restrict__ Tlut) {
    __shared__ float sE[2][128];
    __shared__ float sH[2][128];
    int r = threadIdx.x >> 7;          // 0..1
    int j = threadIdx.x & 127;         // column
    int t = blockIdx.x * 2 + r;

    {
        int jj = j & 63;
        const float Lf = 9.210340371976184f;   // fp32(log(10000))
        float p  = -Lf * (float)jj;
        float ae = p * 0.015625f;
        float freq = (float)exp((double)ae);
        float arg  = (float)t * freq;
        double a = (double)arg;
        sE[r][j] = (j < 64) ? (float)cos(a) : (float)sin(a);
    }
    __syncthreads();
    {
        float acc = b1[j];
        for (int k = 0; k < 128; ++k) acc = fmaf(sE[r][k], W1[k * 128 + j], acc);
        float s = 1.f / (1.f + expf(-acc));
        sH[r][j] = acc * s;
    }
    __syncthreads();
    {
        float acc = b2[j];
        for (int k = 0; k < 128; ++k) acc = fmaf(sH[r][k], W2[k * 128 + j], acc);
        Tlut[(size_t)t * 128 + j] = acc;
    }
}

// ---------------------------------------------------------------------------
// Paired fused dense:  Y = act( A@W1 [+ B@W2] + bias [+ res] )
// A staged in LDS (padded [BM][36]; writes conflict-free, reads broadcast).
// W read DIRECTLY from global (<=256KB, L1/L2-hot, coalesced) - no sW, no
// LDS-pipe bottleneck, no register-prefetch spills.
// Thread owns rows {ty + i*TY} (interleaved: conflict-free sA broadcast) and
// cols {tx*4..+3, NH+tx*4..+3}. RESMODE: 0 none, 2 res[tidx[m]] (LUT gather).
// ---------------------------------------------------------------------------
#define ACT_NONE 0
#define ACT_RELU 1
#define ACT_SILU 2

struct DenseProb {
    const float* A; const float* W1; int K1;
    const float* B; const float* W2; int K2;
    const float* bias; const float* res; const int* tidx;
    float* Y; int M; int nblk;
};

template<int BM, int NOUT, int ACT, bool DUAL, int RESMODE>
__global__ __launch_bounds__(256)
void dense4_kernel(DenseProb q0, DenseProb q1) {
    constexpr int BK = 32;
    constexpr int TX = NOUT / 8;          // 8 cols per thread (two 4-col halves)
    constexpr int TY = 256 / TX;
    constexpr int RM = BM / TY;
    constexpr int NH = NOUT / 2;
    constexpr int AITER = BM / 32;        // float4s per thread staging A

    __shared__ float sA[BM][36];          // row stride 144B = 9*16B: aligned b128, staggered banks

    const bool firstp = (blockIdx.x < (unsigned)q0.nblk);
    const DenseProb& q = firstp ? q0 : q1;
    const int bid = firstp ? blockIdx.x : (blockIdx.x - q0.nblk);

    const int tid = threadIdx.x;
    const int tx  = tid % TX;
    const int ty  = tid / TX;
    const int m0  = bid * BM;

    float acc[RM][8];
#pragma unroll
    for (int i = 0; i < RM; ++i)
#pragma unroll
        for (int j = 0; j < 8; ++j) acc[i][j] = 0.f;

    const int nkt1 = q.K1 / BK;
    const int nkt  = nkt1 + (DUAL ? q.K2 / BK : 0);

    float4 ar[AITER];

    auto issueA = [&](int kt) {
        const float* X; int K; int kk;
        if (!DUAL || kt < nkt1) { X = q.A; K = q.K1; kk = kt * BK; }
        else                    { X = q.B; K = q.K2; kk = (kt - nkt1) * BK; }
#pragma unroll
        for (int r = 0; r < AITER; ++r) {
            int idx = tid + r * 256;
            int row = idx >> 3, kq = idx & 7;
            int m = m0 + row;
            ar[r] = make_float4(0.f, 0.f, 0.f, 0.f);
            if (m < q.M) ar[r] = *reinterpret_cast<const float4*>(X + (size_t)m * K + kk + kq * 4);
        }
    };
    auto commitA = [&]() {
#pragma unroll
        for (int r = 0; r < AITER; ++r) {
            int idx = tid + r * 256;
            int row = idx >> 3, kq = idx & 7;
            *reinterpret_cast<float4*>(&sA[row][kq * 4]) = ar[r];
        }
    };

    issueA(0);
    for (int kt = 0; kt < nkt; ++kt) {
        const float* W; int kk0;
        if (!DUAL || kt < nkt1) { W = q.W1; kk0 = kt * BK; }
        else                    { W = q.W2; kk0 = (kt - nkt1) * BK; }
        commitA();
        __syncthreads();
        if (kt + 1 < nkt) issueA(kt + 1);   // overlap next A-tile global latency
#pragma unroll
        for (int qd = 0; qd < BK / 4; ++qd) {
            float w0[4][4], w1[4][4];
#pragma unroll
            for (int kk = 0; kk < 4; ++kk) {
                const float* wrow = W + (size_t)(kk0 + qd * 4 + kk) * NOUT;
                *reinterpret_cast<float4*>(&w0[kk][0]) = *reinterpret_cast<const float4*>(wrow + tx * 4);
                *reinterpret_cast<float4*>(&w1[kk][0]) = *reinterpret_cast<const float4*>(wrow + NH + tx * 4);
            }
#pragma unroll
            for (int i = 0; i < RM; ++i) {
                float av[4];
                *reinterpret_cast<float4*>(&av[0]) =
                    *reinterpret_cast<const float4*>(&sA[ty + i * TY][qd * 4]);
#pragma unroll
                for (int kk = 0; kk < 4; ++kk) {
#pragma unroll
                    for (int j = 0; j < 4; ++j) {
                        acc[i][j]     = fmaf(av[kk], w0[kk][j], acc[i][j]);
                        acc[i][4 + j] = fmaf(av[kk], w1[kk][j], acc[i][4 + j]);
                    }
                }
            }
        }
        __syncthreads();
    }

    // epilogue
    float bb[8];
    *reinterpret_cast<float4*>(&bb[0]) = *reinterpret_cast<const float4*>(q.bias + tx * 4);
    *reinterpret_cast<float4*>(&bb[4]) = *reinterpret_cast<const float4*>(q.bias + NH + tx * 4);
#pragma unroll
    for (int i = 0; i < RM; ++i) {
        int m = m0 + ty + i * TY;
        if (m >= q.M) continue;
        float v[8];
#pragma unroll
        for (int j = 0; j < 8; ++j) v[j] = acc[i][j] + bb[j];
        if (RESMODE == 2) {
            int tv = q.tidx[m];
            const float* rp = q.res + (size_t)tv * NOUT;
            float4 r0 = *reinterpret_cast<const float4*>(rp + tx * 4);
            float4 r1 = *reinterpret_cast<const float4*>(rp + NH + tx * 4);
            v[0] += r0.x; v[1] += r0.y; v[2] += r0.z; v[3] += r0.w;
            v[4] += r1.x; v[5] += r1.y; v[6] += r1.z; v[7] += r1.w;
        }
#pragma unroll
        for (int j = 0; j < 8; ++j) {
            float x = v[j];
            if (ACT == ACT_RELU) x = fmaxf(x, 0.f);
            else if (ACT == ACT_SILU) { float s = 1.f / (1.f + expf(-x)); x = x * s; }
            v[j] = x;
        }
        *reinterpret_cast<float4*>(q.Y + (size_t)m * NOUT + tx * 4)      = make_float4(v[0], v[1], v[2], v[3]);
        *reinterpret_cast<float4*>(q.Y + (size_t)m * NOUT + NH + tx * 4) = make_float4(v[4], v[5], v[6], v[7]);
    }
}

// ---------------------------------------------------------------------------
// Merged CSR build for both edge sets: histogram -> scan -> atomic fill.
// cnt2/wp2 are [2][50000] contiguous.
// ---------------------------------------------------------------------------
__global__ __launch_bounds__(256) void hist2_kernel(const int* __restrict__ d0,
                                                    const int* __restrict__ d1,
                                                    int* __restrict__ cnt2, int E) {
    int e = blockIdx.x * 256 + threadIdx.x;
    if (e < E) atomicAdd(&cnt2[d0[e]], 1);
    else { e -= E; if (e < E) atomicAdd(&cnt2[NUSER + d1[e]], 1); }
}

#define SCAN_CHUNK 2048
#define GSCAN 25   // ceil(50000/2048)

__global__ __launch_bounds__(256) void scan1x2_kernel(const int* __restrict__ cnt2,
                                                      int* __restrict__ bsum2) {
    __shared__ int sdata[256];
    int p = blockIdx.x / GSCAN, b = blockIdx.x % GSCAN;
    const int* cnt = cnt2 + p * NUSER;
    int base = b * SCAN_CHUNK + threadIdx.x * 8;
    int s = 0;
#pragma unroll
    for (int j = 0; j < 8; ++j) { int i = base + j; if (i < NUSER) s += cnt[i]; }
    sdata[threadIdx.x] = s;
    __syncthreads();
    for (int st = 128; st > 0; st >>= 1) {
        if ((int)threadIdx.x < st) sdata[threadIdx.x] += sdata[threadIdx.x + st];
        __syncthreads();
    }
    if (threadIdx.x == 0) bsum2[p * 32 + b] = sdata[0];
}

__global__ void scan2x2_kernel(int* __restrict__ bsum2) {
    int p = blockIdx.x;
    if (threadIdx.x == 0) {
        int run = 0;
        for (int b = 0; b < GSCAN; ++b) { int v = bsum2[p * 32 + b]; bsum2[p * 32 + b] = run; run += v; }
    }
}

__global__ __launch_bounds__(256) void scan3x2_kernel(const int* __restrict__ cnt2,
                                                      const int* __restrict__ bsum2,
                                                      int* __restrict__ off_ui,
                                                      int* __restrict__ off_iu,
                                                      int* __restrict__ wp2) {
    __shared__ int sth[256];
    int p = blockIdx.x / GSCAN, b = blockIdx.x % GSCAN;
    const int* cnt = cnt2 + p * NUSER;
    int* offs = p ? off_iu : off_ui;
    int* wp = wp2 + p * NUSER;
    int t = threadIdx.x;
    int base = b * SCAN_CHUNK + t * 8;
    int loc[8];
    int s = 0;
#pragma unroll
    for (int j = 0; j < 8; ++j) {
        int i = base + j;
        int v = (i < NUSER) ? cnt[i] : 0;
        loc[j] = s; s += v;
    }
    sth[t] = s;
    __syncthreads();
    for (int st = 1; st < 256; st <<= 1) {
        int v = (t >= st) ? sth[t - st] : 0;
        __syncthreads();
        sth[t] += v;
        __syncthreads();
    }
    int exc = (t == 0) ? 0 : sth[t - 1];
    int boff = bsum2[p * 32 + b];
#pragma unroll
    for (int j = 0; j < 8; ++j) {
        int i = base + j;
        if (i < NUSER) { int o = boff + exc + loc[j]; offs[i] = o; wp[i] = o; }
    }
    if (b == GSCAN - 1 && t == 255) offs[NUSER] = boff + sth[255];
}

__global__ __launch_bounds__(256) void fill2_kernel(const int* __restrict__ s0, const int* __restrict__ d0,
                                                    const int* __restrict__ s1, const int* __restrict__ d1,
                                                    int* __restrict__ wp2,
                                                    int* __restrict__ bkt0, int* __restrict__ bkt1, int E) {
    int e = blockIdx.x * 256 + threadIdx.x;
    if (e < E) {
        int d = d0[e];
        int ppos = atomicAdd(&wp2[d], 1);
        bkt0[ppos] = s0[e];
    } else {
        e -= E;
        if (e < E) {
            int d = d1[e];
            int ppos = atomicAdd(&wp2[NUSER + d], 1);
            bkt1[ppos] = s1[e];
        }
    }
}

// ---------------------------------------------------------------------------
// Paired segment-mean via CSR: one wave per dst row; lanes 0-31 edge e,
// lanes 32-63 edge e+1, float4 per lane; shfl_xor(32) combines halves.
// ---------------------------------------------------------------------------
struct GatherProb { const float* h; const int* offs; const int* bkt; float* out; int N; };

__global__ __launch_bounds__(256)
void gather2_kernel(GatherProb g0, GatherProb g1) {
    int gw = (blockIdx.x * 256 + threadIdx.x) >> 6;
    int lane = threadIdx.x & 63;
    const bool firstp = (gw < g0.N);
    const GatherProb& g = firstp ? g0 : g1;
    int row = firstp ? gw : gw - g0.N;
    if (row >= g.N) return;
    int beg = g.offs[row], end = g.offs[row + 1];
    int half = lane >> 5, c4 = lane & 31;
    const float4* __restrict__ base = reinterpret_cast<const float4*>(g.h);
    float sx = 0.f, sy = 0.f, sz = 0.f, sw = 0.f;
    for (int e = beg + half; e < end; e += 2) {
        int src = g.bkt[e];
        float4 v = base[(size_t)src * 32 + c4];
        sx += v.x; sy += v.y; sz += v.z; sw += v.w;
    }
    sx += __shfl_xor(sx, 32, 64);
    sy += __shfl_xor(sy, 32, 64);
    sz += __shfl_xor(sz, 32, 64);
    sw += __shfl_xor(sw, 32, 64);
    if (half == 0) {
        float d = (float)max(end - beg, 1);
        reinterpret_cast<float4*>(g.out)[(size_t)row * 32 + c4] =
            make_float4(sx / d, sy / d, sz / d, sw / d);
    }
}

// ---------------------------------------------------------------------------
extern "C" void kernel_launch(void* const* d_in, const int* in_sizes, int n_in,
                              void* d_out, int out_size, void* d_ws, size_t ws_size,
                              hipStream_t stream) {
    const float* x_user  = (const float*)d_in[0];
    const float* x_item  = (const float*)d_in[1];
    const int*   t_user  = (const int*)d_in[2];
    const int*   t_item  = (const int*)d_in[3];
    const int*   eui_src = (const int*)d_in[4];
    const int*   eui_dst = (const int*)d_in[5];
    const int*   eiu_src = (const int*)d_in[6];
    const int*   eiu_dst = (const int*)d_in[7];
    const float* te_W1 = (const float*)d_in[8];  const float* te_b1 = (const float*)d_in[9];
    const float* te_W2 = (const float*)d_in[10]; const float* te_b2 = (const float*)d_in[11];
    const float* proj_Wu = (const float*)d_in[12]; const float* proj_bu = (const float*)d_in[13];
    const float* proj_Wi = (const float*)d_in[14]; const float* proj_bi = (const float*)d_in[15];
    const float* sage_Wnbr  = (const float*)d_in[16];
    const float* sage_Wroot = (const float*)d_in[17];
    const float* sage_b     = (const float*)d_in[18];
    const float* mu_W1 = (const float*)d_in[19]; const float* mu_b1 = (const float*)d_in[20];
    const float* mu_W2 = (const float*)d_in[21]; const float* mu_b2 = (const float*)d_in[22];
    const float* mu_W3 = (const float*)d_in[23]; const float* mu_b3 = (const float*)d_in[24];
    const float* mi_W1 = (const float*)d_in[25]; const float* mi_b1 = (const float*)d_in[26];
    const float* mi_W2 = (const float*)d_in[27]; const float* mi_b2 = (const float*)d_in[28];
    const float* mi_W3 = (const float*)d_in[29]; const float* mi_b3 = (const float*)d_in[30];

    float* out_u = (float*)d_out;                  // [25000][64]
    float* out_i = out_u + (size_t)NIN * 64;       // [25000][32]

    const size_t NBIG = (size_t)NUSER * DIMT;      // 6.4M floats (25.6 MB)
    float* ws = (float*)d_ws;
    float* P0 = ws;
    float* P1 = ws + NBIG;
    float* P2 = ws + 2 * NBIG;
    float* P3 = ws + 3 * NBIG;
    float* Tlut = ws + 4 * NBIG;                   // 1000*128
    int* ip = (int*)(Tlut + NTVAL * 128);
    int* cnt2   = ip;  ip += 2 * NUSER;            // [2][50000]
    int* wp2    = ip;  ip += 2 * NUSER;
    int* off_ui = ip;  ip += NUSER + 1;
    int* off_iu = ip;  ip += NUSER + 1;
    int* bkt_ui = ip;  ip += NEDGE;
    int* bkt_iu = ip;  ip += NEDGE;
    int* bsum2  = ip;  ip += 64;

    const int nb128_50k = (NUSER + 127) / 128;     // 391
    const int nb64_25k  = (NIN + 63) / 64;         // 391
    const int nb128_25k = (NIN + 127) / 128;       // 196
    const int nb256_25k = (NIN + 255) / 256;       // 98
    const int gEdges2 = (2 * NEDGE + 255) / 256;   // 4688

    DenseProb qn = {};  // null slot

    // ---- timestep-MLP LUT ----
    lut_mlp_kernel<<<NTVAL / 2, 256, 0, stream>>>(te_W1, te_b1, te_W2, te_b2, Tlut);

    // ---- proj (merged user+item): h = x@proj_W + b + Tlut[t] ----
    {
        DenseProb qu = { x_user, proj_Wu, 64, nullptr, nullptr, 0, proj_bu, Tlut, t_user, P0, NUSER, nb128_50k };
        DenseProb qi = { x_item, proj_Wi, 32, nullptr, nullptr, 0, proj_bi, Tlut, t_item, P1, NITEM, nb128_50k };
        dense4_kernel<128, 128, ACT_NONE, false, 2><<<2 * nb128_50k, 256, 0, stream>>>(qu, qi);
    }

    // ---- CSR build (both edge sets merged) ----
    hipMemsetAsync(cnt2, 0, 2 * NUSER * sizeof(int), stream);
    hist2_kernel<<<gEdges2, 256, 0, stream>>>(eui_dst, eiu_dst, cnt2, NEDGE);
    scan1x2_kernel<<<2 * GSCAN, 256, 0, stream>>>(cnt2, bsum2);
    scan2x2_kernel<<<2, 64, 0, stream>>>(bsum2);
    scan3x2_kernel<<<2 * GSCAN, 256, 0, stream>>>(cnt2, bsum2, off_ui, off_iu, wp2);
    fill2_kernel<<<gEdges2, 256, 0, stream>>>(eui_src, eui_dst, eiu_src, eiu_dst, wp2, bkt_ui, bkt_iu, NEDGE);

    // ---- SAGE layers (gather pair merged, dense pair merged) ----
    float* hu = P0; float* hi = P1; float* fa = P2; float* fb = P3;
    for (int l = 0; l < 2; ++l) {
        const float* Wn0 = sage_Wnbr  + (size_t)(l * 2 + 0) * DIMT * DIMT;
        const float* Wr0 = sage_Wroot + (size_t)(l * 2 + 0) * DIMT * DIMT;
        const float* sb0 = sage_b     + (size_t)(l * 2 + 0) * DIMT;
        const float* Wn1 = sage_Wnbr  + (size_t)(l * 2 + 1) * DIMT * DIMT;
        const float* Wr1 = sage_Wroot + (size_t)(l * 2 + 1) * DIMT * DIMT;
        const float* sb1 = sage_b     + (size_t)(l * 2 + 1) * DIMT;

        {
            GatherProb gi = { hu, off_ui, bkt_ui, fa, NITEM };
            GatherProb gu = { hi, off_iu, bkt_iu, fb, NUSER };
            gather2_kernel<<<(NITEM + NUSER) * 64 / 256, 256, 0, stream>>>(gi, gu);
        }
        {
            DenseProb qi = { fa, Wn0, DIMT, hi, Wr0, DIMT, sb0, nullptr, nullptr, fa, NITEM, nb128_50k };
            DenseProb qu = { fb, Wn1, DIMT, hu, Wr1, DIMT, sb1, nullptr, nullptr, fb, NUSER, nb128_50k };
            dense4_kernel<128, 128, ACT_RELU, true, 0><<<2 * nb128_50k, 256, 0, stream>>>(qi, qu);
        }
        float* ohu = hu; float* ohi = hi;
        hi = fa; hu = fb; fa = ohu; fb = ohi;
    }

    // ---- MLP heads (first 25000 rows; user/item merged per level) ----
    float* T0 = fa;
    float* T1 = fb;
    {
        DenseProb qu = { hu, mu_W1, 128, nullptr, nullptr, 0, mu_b1, nullptr, nullptr, T0, NIN, nb64_25k };
        DenseProb qi = { hi, mi_W1, 128, nullptr, nullptr, 0, mi_b1, nullptr, nullptr, T1, NIN, nb64_25k };
        dense4_kernel<64, 256, ACT_RELU, false, 0><<<2 * nb64_25k, 256, 0, stream>>>(qu, qi);
    }
    {
        DenseProb qu = { T0, mu_W2, 256, nullptr, nullptr, 0, mu_b2, nullptr, nullptr, T0, NIN, nb64_25k };
        DenseProb qi = { T1, mi_W2, 256, nullptr, nullptr, 0, mi_b2, nullptr, nullptr, T1, NIN, nb64_25k };
        dense4_kernel<64, 256, ACT_RELU, false, 0><<<2 * nb64_25k, 256, 0, stream>>>(qu, qi);
    }
    {
        DenseProb q = { T0, mu_W3, 256, nullptr, nullptr, 0, mu_b3, nullptr, nullptr, out_u, NIN, nb128_25k };
        dense4_kernel<128, 64, ACT_NONE, false, 0><<<nb128_25k, 256, 0, stream>>>(q, qn);
    }
    {
        DenseProb q = { T1, mi_W3, 256, nullptr, nullptr, 0, mi_b3, nullptr, nullptr, out_i, NIN, nb256_25k };
        dense4_kernel<256, 32, ACT_NONE, false, 0><<<nb256_25k, 256, 0, stream>>>(q, qn);
    }

    (void)in_sizes; (void)n_in; (void)out_size; (void)ws_size;
}

// Round 5
// 705.568 us; speedup vs baseline: 1.7714x; 1.1326x over previous
//
#include <hip/hip_runtime.h>
#include <math.h>

#define NEDGE 600000
#define NUSER 50000
#define NITEM 50000
#define DIMT  128
#define NIN   25000
#define NTVAL 1000

typedef unsigned short ushort_t;
typedef __attribute__((ext_vector_type(8))) short bf16x8;
typedef __attribute__((ext_vector_type(4))) float f32x4;

__device__ __forceinline__ void split_bf16(float f, ushort_t& h, ushort_t& l) {
    unsigned u = __float_as_uint(f);
    unsigned r = u + 0x7fffu + ((u >> 16) & 1u);
    h = (ushort_t)(r >> 16);
    float fh = __uint_as_float((unsigned)h << 16);
    float fl = f - fh;                      // exact (Sterbenz)
    unsigned ul = __float_as_uint(fl);
    unsigned rl = ul + 0x7fffu + ((ul >> 16) & 1u);
    l = (ushort_t)(rl >> 16);
}
__device__ __forceinline__ float bf16_f(ushort_t h) {
    return __uint_as_float((unsigned)h << 16);
}

// ---------------------------------------------------------------------------
// Fused timestep-MLP LUT (fp32, numpy-rounding-exact emb; trig in f64)
// ---------------------------------------------------------------------------
__global__ __launch_bounds__(256) void lut_mlp_kernel(
        const float* __restrict__ W1, const float* __restrict__ b1,
        const float* __restrict__ W2, const float* __restrict__ b2,
        float* __restrict__ Tlut) {
    __shared__ float sE[2][128];
    __shared__ float sH[2][128];
    int r = threadIdx.x >> 7;
    int j = threadIdx.x & 127;
    int t = blockIdx.x * 2 + r;
    {
        int jj = j & 63;
        const float Lf = 9.210340371976184f;
        float p  = -Lf * (float)jj;
        float ae = p * 0.015625f;
        float freq = (float)exp((double)ae);
        float arg  = (float)t * freq;
        double a = (double)arg;
        sE[r][j] = (j < 64) ? (float)cos(a) : (float)sin(a);
    }
    __syncthreads();
    {
        float acc = b1[j];
        for (int k = 0; k < 128; ++k) acc = fmaf(sE[r][k], W1[k * 128 + j], acc);
        float s = 1.f / (1.f + expf(-acc));
        sH[r][j] = acc * s;
    }
    __syncthreads();
    {
        float acc = b2[j];
        for (int k = 0; k < 128; ++k) acc = fmaf(sH[r][k], W2[k * 128 + j], acc);
        Tlut[(size_t)t * 128 + j] = acc;
    }
}

// ---------------------------------------------------------------------------
// Weight convert+transpose: W[K][N] fp32 -> WT_hi[N][K], WT_lo[N][K] bf16
// ---------------------------------------------------------------------------
struct WDesc { const float* src; int K; int N; unsigned dst; };
struct WDescs { WDesc d[16]; };

__global__ __launch_bounds__(256) void cvtw_kernel(WDescs ds, ushort_t* __restrict__ pool) {
    int gtid = blockIdx.x * 256 + threadIdx.x;
    int gsz = gridDim.x * 256;
#pragma unroll 1
    for (int i = 0; i < 16; ++i) {
        const WDesc w = ds.d[i];
        int sz = w.K * w.N;
        ushort_t* ph = pool + w.dst;
        ushort_t* pl = ph + sz;
        for (int e = gtid; e < sz; e += gsz) {
            int k = e / w.N, n = e - k * w.N;
            ushort_t h, l;
            split_bf16(w.src[e], h, l);
            ph[(size_t)n * w.K + k] = h;
            pl[(size_t)n * w.K + k] = l;
        }
    }
}

// ---------------------------------------------------------------------------
// Input split: fp32 matrix -> hi/lo planes (for x_user / x_item)
// ---------------------------------------------------------------------------
__global__ __launch_bounds__(256) void cvtx_kernel(
        const float* __restrict__ x0, int n0, ushort_t* __restrict__ h0, ushort_t* __restrict__ l0,
        const float* __restrict__ x1, int n1, ushort_t* __restrict__ h1, ushort_t* __restrict__ l1) {
    int g = blockIdx.x * 256 + threadIdx.x;
    int gs = gridDim.x * 256;
    for (int i = g; i < n0; i += gs) { ushort_t h, l; split_bf16(x0[i], h, l); h0[i] = h; l0[i] = l; }
    for (int i = g; i < n1; i += gs) { ushort_t h, l; split_bf16(x1[i], h, l); h1[i] = h; l1[i] = l; }
}

// ---------------------------------------------------------------------------
// MFMA GEMM (split-bf16, 3-pass):  Y = act( A@W1 [+ A2@W2] + bias [+ res] )
// A given as hi/lo bf16 planes [M][K]; W given transposed hi/lo [NOUT][K].
// Block = 4 waves; wave tile 64 x min(64,NOUT); no LDS; frags from L1/L2.
// OUTMODE bit0: fp32 Y; bit1: hi/lo planes. RESMODE 2: += Tlut[tidx[m]].
// ---------------------------------------------------------------------------
#define ACT_NONE 0
#define ACT_RELU 1

struct MProb {
    const ushort_t *A1h, *A1l; int K1;
    const ushort_t *A2h, *A2l; int K2;
    const ushort_t *W1, *W2;            // hilo concat: lo plane at +NOUT*K
    const float* bias; const float* res; const int* tidx;
    float* Yf; ushort_t *Yh, *Yl;
    int M; int nblk;
};

template<int NOUT, int ACT, bool DUAL, int RESMODE, int OUTMODE>
__global__ __launch_bounds__(256)
void mgemm_kernel(MProb q0, MProb q1) {
    constexpr int WN  = (NOUT >= 64) ? 64 : NOUT;
    constexpr int NWC = NOUT / WN;
    constexpr int NWR = 4 / NWC;
    constexpr int BM  = NWR * 64;
    constexpr int NF  = WN / 16;

    const bool firstp = (blockIdx.x < (unsigned)q0.nblk);
    const MProb& q = firstp ? q0 : q1;
    const int bid = firstp ? blockIdx.x : (blockIdx.x - q0.nblk);

    const int w    = threadIdx.x >> 6;
    const int lane = threadIdx.x & 63;
    const int wc   = w % NWC;
    const int wr   = w / NWC;
    const int mw   = bid * BM + wr * 64;
    const int nw   = wc * WN;
    const int lr   = lane & 15;
    const int lkg  = lane >> 4;

    f32x4 acc[4][NF];
#pragma unroll
    for (int i = 0; i < 4; ++i)
#pragma unroll
        for (int j = 0; j < NF; ++j) acc[i][j] = (f32x4)0.f;

    const bf16x8 zf = {0,0,0,0,0,0,0,0};

    const int nph = DUAL ? 2 : 1;
#pragma unroll 1
    for (int ph = 0; ph < nph; ++ph) {
        const ushort_t* Ah = ph ? q.A2h : q.A1h;
        const ushort_t* Al = ph ? q.A2l : q.A1l;
        const int K        = ph ? q.K2  : q.K1;
        const ushort_t* Wh = ph ? q.W2  : q.W1;
        const ushort_t* Wl = Wh + (size_t)NOUT * K;
#pragma unroll 1
        for (int k0 = 0; k0 < K; k0 += 32) {
            const int kb = k0 + lkg * 8;
            bf16x8 a_h[4], a_l[4], b_h[NF], b_l[NF];
#pragma unroll
            for (int mf = 0; mf < 4; ++mf) {
                int row = mw + mf * 16 + lr;
                if (row < q.M) {
                    a_h[mf] = *reinterpret_cast<const bf16x8*>(Ah + (size_t)row * K + kb);
                    a_l[mf] = *reinterpret_cast<const bf16x8*>(Al + (size_t)row * K + kb);
                } else { a_h[mf] = zf; a_l[mf] = zf; }
            }
#pragma unroll
            for (int nf = 0; nf < NF; ++nf) {
                int col = nw + nf * 16 + lr;
                b_h[nf] = *reinterpret_cast<const bf16x8*>(Wh + (size_t)col * K + kb);
                b_l[nf] = *reinterpret_cast<const bf16x8*>(Wl + (size_t)col * K + kb);
            }
#pragma unroll
            for (int mf = 0; mf < 4; ++mf)
#pragma unroll
                for (int nf = 0; nf < NF; ++nf) {
                    acc[mf][nf] = __builtin_amdgcn_mfma_f32_16x16x32_bf16(a_h[mf], b_h[nf], acc[mf][nf], 0, 0, 0);
                    acc[mf][nf] = __builtin_amdgcn_mfma_f32_16x16x32_bf16(a_h[mf], b_l[nf], acc[mf][nf], 0, 0, 0);
                    acc[mf][nf] = __builtin_amdgcn_mfma_f32_16x16x32_bf16(a_l[mf], b_h[nf], acc[mf][nf], 0, 0, 0);
                }
        }
    }

    // all reads done before any in-place epilogue store (waves share rows)
    __syncthreads();

    float bcol[NF];
#pragma unroll
    for (int nf = 0; nf < NF; ++nf) bcol[nf] = q.bias[nw + nf * 16 + lr];

#pragma unroll
    for (int mf = 0; mf < 4; ++mf) {
#pragma unroll
        for (int r = 0; r < 4; ++r) {
            int row = mw + mf * 16 + lkg * 4 + r;
            if (row >= q.M) continue;
            const float* rp = nullptr;
            if (RESMODE == 2) { int tv = q.tidx[row]; rp = q.res + (size_t)tv * NOUT; }
#pragma unroll
            for (int nf = 0; nf < NF; ++nf) {
                int col = nw + nf * 16 + lr;
                float v = acc[mf][nf][r] + bcol[nf];
                if (RESMODE == 2) v += rp[col];
                if (ACT == ACT_RELU) v = fmaxf(v, 0.f);
                size_t o = (size_t)row * NOUT + col;
                if (OUTMODE & 1) q.Yf[o] = v;
                if (OUTMODE & 2) {
                    ushort_t h, l;
                    split_bf16(v, h, l);
                    q.Yh[o] = h; q.Yl[o] = l;
                }
            }
        }
    }
}

// ---------------------------------------------------------------------------
// Merged CSR build (both edge sets)
// ---------------------------------------------------------------------------
__global__ __launch_bounds__(256) void hist2_kernel(const int* __restrict__ d0,
                                                    const int* __restrict__ d1,
                                                    int* __restrict__ cnt2, int E) {
    int e = blockIdx.x * 256 + threadIdx.x;
    if (e < E) atomicAdd(&cnt2[d0[e]], 1);
    else { e -= E; if (e < E) atomicAdd(&cnt2[NUSER + d1[e]], 1); }
}

#define SCAN_CHUNK 2048
#define GSCAN 25

__global__ __launch_bounds__(256) void scan1x2_kernel(const int* __restrict__ cnt2,
                                                      int* __restrict__ bsum2) {
    __shared__ int sdata[256];
    int p = blockIdx.x / GSCAN, b = blockIdx.x % GSCAN;
    const int* cnt = cnt2 + p * NUSER;
    int base = b * SCAN_CHUNK + threadIdx.x * 8;
    int s = 0;
#pragma unroll
    for (int j = 0; j < 8; ++j) { int i = base + j; if (i < NUSER) s += cnt[i]; }
    sdata[threadIdx.x] = s;
    __syncthreads();
    for (int st = 128; st > 0; st >>= 1) {
        if ((int)threadIdx.x < st) sdata[threadIdx.x] += sdata[threadIdx.x + st];
        __syncthreads();
    }
    if (threadIdx.x == 0) bsum2[p * 32 + b] = sdata[0];
}

__global__ void scan2x2_kernel(int* __restrict__ bsum2) {
    int p = blockIdx.x;
    if (threadIdx.x == 0) {
        int run = 0;
        for (int b = 0; b < GSCAN; ++b) { int v = bsum2[p * 32 + b]; bsum2[p * 32 + b] = run; run += v; }
    }
}

__global__ __launch_bounds__(256) void scan3x2_kernel(const int* __restrict__ cnt2,
                                                      const int* __restrict__ bsum2,
                                                      int* __restrict__ off_ui,
                                                      int* __restrict__ off_iu,
                                                      int* __restrict__ wp2) {
    __shared__ int sth[256];
    int p = blockIdx.x / GSCAN, b = blockIdx.x % GSCAN;
    const int* cnt = cnt2 + p * NUSER;
    int* offs = p ? off_iu : off_ui;
    int* wp = wp2 + p * NUSER;
    int t = threadIdx.x;
    int base = b * SCAN_CHUNK + t * 8;
    int loc[8];
    int s = 0;
#pragma unroll
    for (int j = 0; j < 8; ++j) {
        int i = base + j;
        int v = (i < NUSER) ? cnt[i] : 0;
        loc[j] = s; s += v;
    }
    sth[t] = s;
    __syncthreads();
    for (int st = 1; st < 256; st <<= 1) {
        int v = (t >= st) ? sth[t - st] : 0;
        __syncthreads();
        sth[t] += v;
        __syncthreads();
    }
    int exc = (t == 0) ? 0 : sth[t - 1];
    int boff = bsum2[p * 32 + b];
#pragma unroll
    for (int j = 0; j < 8; ++j) {
        int i = base + j;
        if (i < NUSER) { int o = boff + exc + loc[j]; offs[i] = o; wp[i] = o; }
    }
    if (b == GSCAN - 1 && t == 255) offs[NUSER] = boff + sth[255];
}

__global__ __launch_bounds__(256) void fill2_kernel(const int* __restrict__ s0, const int* __restrict__ d0,
                                                    const int* __restrict__ s1, const int* __restrict__ d1,
                                                    int* __restrict__ wp2,
                                                    int* __restrict__ bkt0, int* __restrict__ bkt1, int E) {
    int e = blockIdx.x * 256 + threadIdx.x;
    if (e < E) {
        int d = d0[e];
        int p = atomicAdd(&wp2[d], 1);
        bkt0[p] = s0[e];
    } else {
        e -= E;
        if (e < E) {
            int d = d1[e];
            int p = atomicAdd(&wp2[NUSER + d], 1);
            bkt1[p] = s1[e];
        }
    }
}

// ---------------------------------------------------------------------------
// Paired segment-mean from hi/lo planes -> mean hi/lo planes.
// One wave per dst row; halves handle alternate edges; lane covers 4 cols.
// ---------------------------------------------------------------------------
struct GProb { const ushort_t* Hh; const ushort_t* Hl; const int* offs; const int* bkt;
               ushort_t* Oh; ushort_t* Ol; int N; };

__global__ __launch_bounds__(256)
void gather2m_kernel(GProb g0, GProb g1) {
    int gw = (blockIdx.x * 256 + threadIdx.x) >> 6;
    int lane = threadIdx.x & 63;
    const bool firstp = (gw < g0.N);
    const GProb& g = firstp ? g0 : g1;
    int row = firstp ? gw : gw - g0.N;
    if (row >= g.N) return;
    int beg = g.offs[row], end = g.offs[row + 1];
    int half = lane >> 5, c = lane & 31;        // cols 4c..4c+3
    float s0 = 0.f, s1 = 0.f, s2 = 0.f, s3 = 0.f;
    for (int e = beg + half; e < end; e += 2) {
        int src = g.bkt[e];
        ushort4 vh = *reinterpret_cast<const ushort4*>(g.Hh + (size_t)src * 128 + 4 * c);
        ushort4 vl = *reinterpret_cast<const ushort4*>(g.Hl + (size_t)src * 128 + 4 * c);
        s0 += bf16_f(vh.x) + bf16_f(vl.x);
        s1 += bf16_f(vh.y) + bf16_f(vl.y);
        s2 += bf16_f(vh.z) + bf16_f(vl.z);
        s3 += bf16_f(vh.w) + bf16_f(vl.w);
    }
    s0 += __shfl_xor(s0, 32, 64);
    s1 += __shfl_xor(s1, 32, 64);
    s2 += __shfl_xor(s2, 32, 64);
    s3 += __shfl_xor(s3, 32, 64);
    if (half == 0) {
        float d = (float)max(end - beg, 1);
        float m0 = s0 / d, m1 = s1 / d, m2 = s2 / d, m3 = s3 / d;
        ushort4 oh, ol;
        split_bf16(m0, oh.x, ol.x);
        split_bf16(m1, oh.y, ol.y);
        split_bf16(m2, oh.z, ol.z);
        split_bf16(m3, oh.w, ol.w);
        *reinterpret_cast<ushort4*>(g.Oh + (size_t)row * 128 + 4 * c) = oh;
        *reinterpret_cast<ushort4*>(g.Ol + (size_t)row * 128 + 4 * c) = ol;
    }
}

// ---------------------------------------------------------------------------
extern "C" void kernel_launch(void* const* d_in, const int* in_sizes, int n_in,
                              void* d_out, int out_size, void* d_ws, size_t ws_size,
                              hipStream_t stream) {
    const float* x_user  = (const float*)d_in[0];
    const float* x_item  = (const float*)d_in[1];
    const int*   t_user  = (const int*)d_in[2];
    const int*   t_item  = (const int*)d_in[3];
    const int*   eui_src = (const int*)d_in[4];
    const int*   eui_dst = (const int*)d_in[5];
    const int*   eiu_src = (const int*)d_in[6];
    const int*   eiu_dst = (const int*)d_in[7];
    const float* te_W1 = (const float*)d_in[8];  const float* te_b1 = (const float*)d_in[9];
    const float* te_W2 = (const float*)d_in[10]; const float* te_b2 = (const float*)d_in[11];
    const float* proj_Wu = (const float*)d_in[12]; const float* proj_bu = (const float*)d_in[13];
    const float* proj_Wi = (const float*)d_in[14]; const float* proj_bi = (const float*)d_in[15];
    const float* sage_Wnbr  = (const float*)d_in[16];
    const float* sage_Wroot = (const float*)d_in[17];
    const float* sage_b     = (const float*)d_in[18];
    const float* mu_W1 = (const float*)d_in[19]; const float* mu_b1 = (const float*)d_in[20];
    const float* mu_W2 = (const float*)d_in[21]; const float* mu_b2 = (const float*)d_in[22];
    const float* mu_W3 = (const float*)d_in[23]; const float* mu_b3 = (const float*)d_in[24];
    const float* mi_W1 = (const float*)d_in[25]; const float* mi_b1 = (const float*)d_in[26];
    const float* mi_W2 = (const float*)d_in[27]; const float* mi_b2 = (const float*)d_in[28];
    const float* mi_W3 = (const float*)d_in[29]; const float* mi_b3 = (const float*)d_in[30];

    float* out_u = (float*)d_out;                  // [25000][64]
    float* out_i = out_u + (size_t)NIN * 64;       // [25000][32]

    // ---- workspace layout ----
    float* Tlut = (float*)d_ws;                    // 1000*128 fp32
    ushort_t* u16b = (ushort_t*)(Tlut + NTVAL * 128);
    const size_t PL = (size_t)NUSER * DIMT;        // 6.4M elems per plane
    ushort_t* Hh_u = u16b;
    ushort_t* Hl_u = u16b + PL;
    ushort_t* Hh_i = u16b + 2 * PL;
    ushort_t* Hl_i = u16b + 3 * PL;
    ushort_t* G0   = u16b + 4 * PL;                // 4 planes: gather means / x-planes / head temps
    ushort_t* Gh_i = G0;            ushort_t* Gl_i = G0 + PL;
    ushort_t* Gh_u = G0 + 2 * PL;   ushort_t* Gl_u = G0 + 3 * PL;
    ushort_t* WT   = u16b + 8 * PL;

    // weight descriptor table (16 entries)
    WDescs wd;
    unsigned woff[16];
    unsigned off = 0; int wi = 0;
    auto addw = [&](const float* src, int K, int N) {
        wd.d[wi].src = src; wd.d[wi].K = K; wd.d[wi].N = N; wd.d[wi].dst = off;
        woff[wi] = off; off += 2u * K * N; ++wi;
    };
    addw(proj_Wu, 64, 128);                                    // 0
    addw(proj_Wi, 32, 128);                                    // 1
    for (int l = 0; l < 2; ++l)
        for (int e = 0; e < 2; ++e)
            addw(sage_Wnbr + (size_t)(l * 2 + e) * DIMT * DIMT, 128, 128);   // 2..5
    for (int l = 0; l < 2; ++l)
        for (int e = 0; e < 2; ++e)
            addw(sage_Wroot + (size_t)(l * 2 + e) * DIMT * DIMT, 128, 128);  // 6..9
    addw(mu_W1, 128, 256);                                     // 10
    addw(mu_W2, 256, 256);                                     // 11
    addw(mu_W3, 256, 64);                                      // 12
    addw(mi_W1, 128, 256);                                     // 13
    addw(mi_W2, 256, 256);                                     // 14
    addw(mi_W3, 256, 32);                                      // 15

    int* ip = (int*)(WT + off + (off & 1));
    int* cnt2   = ip;  ip += 2 * NUSER;
    int* wp2    = ip;  ip += 2 * NUSER;
    int* off_ui = ip;  ip += NUSER + 1;
    int* off_iu = ip;  ip += NUSER + 1;
    int* bkt_ui = ip;  ip += NEDGE;
    int* bkt_iu = ip;  ip += NEDGE;
    int* bsum2  = ip;  ip += 64;

    const int gEdges2 = (2 * NEDGE + 255) / 256;
    MProb qn = {}; qn.nblk = 0;

    // ---- LUT + weight/input conversion ----
    lut_mlp_kernel<<<NTVAL / 2, 256, 0, stream>>>(te_W1, te_b1, te_W2, te_b2, Tlut);
    cvtw_kernel<<<256, 256, 0, stream>>>(wd, WT);
    // x planes live in the G region until proj is done
    ushort_t* xu_h = Gh_i; ushort_t* xu_l = Gl_i;
    ushort_t* xi_h = Gh_u; ushort_t* xi_l = Gl_u;
    cvtx_kernel<<<512, 256, 0, stream>>>(x_user, NUSER * 64, xu_h, xu_l,
                                         x_item, NITEM * 32, xi_h, xi_l);

    // ---- CSR build ----
    hipMemsetAsync(cnt2, 0, 2 * NUSER * sizeof(int), stream);
    hist2_kernel<<<gEdges2, 256, 0, stream>>>(eui_dst, eiu_dst, cnt2, NEDGE);
    scan1x2_kernel<<<2 * GSCAN, 256, 0, stream>>>(cnt2, bsum2);
    scan2x2_kernel<<<2, 64, 0, stream>>>(bsum2);
    scan3x2_kernel<<<2 * GSCAN, 256, 0, stream>>>(cnt2, bsum2, off_ui, off_iu, wp2);
    fill2_kernel<<<gEdges2, 256, 0, stream>>>(eui_src, eui_dst, eiu_src, eiu_dst, wp2, bkt_ui, bkt_iu, NEDGE);

    // ---- proj: h = x@W + b + Tlut[t]  (NOUT=128, BM=128 -> nblk 391) ----
    {
        MProb qu = {}; MProb qi = {};
        qu.A1h = xu_h; qu.A1l = xu_l; qu.K1 = 64;
        qu.W1 = WT + woff[0]; qu.bias = proj_bu; qu.res = Tlut; qu.tidx = t_user;
        qu.Yh = Hh_u; qu.Yl = Hl_u; qu.M = NUSER; qu.nblk = (NUSER + 127) / 128;
        qi.A1h = xi_h; qi.A1l = xi_l; qi.K1 = 32;
        qi.W1 = WT + woff[1]; qi.bias = proj_bi; qi.res = Tlut; qi.tidx = t_item;
        qi.Yh = Hh_i; qi.Yl = Hl_i; qi.M = NITEM; qi.nblk = (NITEM + 127) / 128;
        mgemm_kernel<128, ACT_NONE, false, 2, 2><<<qu.nblk + qi.nblk, 256, 0, stream>>>(qu, qi);
    }

    // ---- SAGE layers: gather (paired) then dual GEMM (paired), in-place H ----
    for (int l = 0; l < 2; ++l) {
        {
            GProb gi = { Hh_u, Hl_u, off_ui, bkt_ui, Gh_i, Gl_i, NITEM };
            GProb gu = { Hh_i, Hl_i, off_iu, bkt_iu, Gh_u, Gl_u, NUSER };
            gather2m_kernel<<<(NITEM + NUSER) * 64 / 256, 256, 0, stream>>>(gi, gu);
        }
        {
            MProb qi = {}; MProb qu = {};
            qi.A1h = Gh_i; qi.A1l = Gl_i; qi.K1 = 128;
            qi.A2h = Hh_i; qi.A2l = Hl_i; qi.K2 = 128;
            qi.W1 = WT + woff[2 + l * 2 + 0]; qi.W2 = WT + woff[6 + l * 2 + 0];
            qi.bias = sage_b + (size_t)(l * 2 + 0) * DIMT;
            qi.Yh = Hh_i; qi.Yl = Hl_i; qi.M = NITEM; qi.nblk = (NITEM + 127) / 128;
            qu.A1h = Gh_u; qu.A1l = Gl_u; qu.K1 = 128;
            qu.A2h = Hh_u; qu.A2l = Hl_u; qu.K2 = 128;
            qu.W1 = WT + woff[2 + l * 2 + 1]; qu.W2 = WT + woff[6 + l * 2 + 1];
            qu.bias = sage_b + (size_t)(l * 2 + 1) * DIMT;
            qu.Yh = Hh_u; qu.Yl = Hl_u; qu.M = NUSER; qu.nblk = (NUSER + 127) / 128;
            mgemm_kernel<128, ACT_RELU, true, 0, 2><<<qi.nblk + qu.nblk, 256, 0, stream>>>(qi, qu);
        }
    }

    // ---- MLP heads (rows 0..25000). T planes reuse the G region. ----
    ushort_t* Th_u = G0;            ushort_t* Tl_u = G0 + PL;
    ushort_t* Th_i = G0 + 2 * PL;   ushort_t* Tl_i = G0 + 3 * PL;
    {
        MProb qu = {}; MProb qi = {};
        qu.A1h = Hh_u; qu.A1l = Hl_u; qu.K1 = 128;
        qu.W1 = WT + woff[10]; qu.bias = mu_b1;
        qu.Yh = Th_u; qu.Yl = Tl_u; qu.M = NIN; qu.nblk = (NIN + 63) / 64;
        qi.A1h = Hh_i; qi.A1l = Hl_i; qi.K1 = 128;
        qi.W1 = WT + woff[13]; qi.bias = mi_b1;
        qi.Yh = Th_i; qi.Yl = Tl_i; qi.M = NIN; qi.nblk = (NIN + 63) / 64;
        mgemm_kernel<256, ACT_RELU, false, 0, 2><<<qu.nblk + qi.nblk, 256, 0, stream>>>(qu, qi);
    }
    {
        MProb qu = {}; MProb qi = {};
        qu.A1h = Th_u; qu.A1l = Tl_u; qu.K1 = 256;
        qu.W1 = WT + woff[11]; qu.bias = mu_b2;
        qu.Yh = Th_u; qu.Yl = Tl_u; qu.M = NIN; qu.nblk = (NIN + 63) / 64;   // in-place
        qi.A1h = Th_i; qi.A1l = Tl_i; qi.K1 = 256;
        qi.W1 = WT + woff[14]; qi.bias = mi_b2;
        qi.Yh = Th_i; qi.Yl = Tl_i; qi.M = NIN; qi.nblk = (NIN + 63) / 64;
        mgemm_kernel<256, ACT_RELU, false, 0, 2><<<qu.nblk + qi.nblk, 256, 0, stream>>>(qu, qi);
    }
    {
        MProb q = {};
        q.A1h = Th_u; q.A1l = Tl_u; q.K1 = 256;
        q.W1 = WT + woff[12]; q.bias = mu_b3;
        q.Yf = out_u; q.M = NIN; q.nblk = (NIN + 255) / 256;
        mgemm_kernel<64, ACT_NONE, false, 0, 1><<<q.nblk, 256, 0, stream>>>(q, qn);
    }
    {
        MProb q = {};
        q.A1h = Th_i; q.A1l = Tl_i; q.K1 = 256;
        q.W1 = WT + woff[15]; q.bias = mi_b3;
        q.Yf = out_i; q.M = NIN; q.nblk = (NIN + 255) / 256;
        mgemm_kernel<32, ACT_NONE, false, 0, 1><<<q.nblk, 256, 0, stream>>>(q, qn);
    }

    (void)in_sizes; (void)n_in; (void)out_size; (void)ws_size;
}

// Round 6
// 635.154 us; speedup vs baseline: 1.9678x; 1.1109x over previous
//
#include <hip/hip_runtime.h>
#include <math.h>

#define NEDGE 600000
#define NUSER 50000
#define NITEM 50000
#define DIMT  128
#define NIN   25000
#define NTVAL 1000

typedef unsigned short ushort_t;
typedef __attribute__((ext_vector_type(8))) short bf16x8;
typedef __attribute__((ext_vector_type(4))) float f32x4;
typedef __attribute__((ext_vector_type(4))) unsigned upk4;

// packed element: low16 = hi bf16, high16 = lo bf16 ; value = fh + fl
__device__ __forceinline__ unsigned pack_hl(float f) {
    unsigned u = __float_as_uint(f);
    unsigned r = u + 0x7fffu + ((u >> 16) & 1u);
    unsigned h = (r >> 16) & 0xffffu;
    float fh = __uint_as_float(h << 16);
    float fl = f - fh;
    unsigned ul = __float_as_uint(fl);
    unsigned rl = ul + 0x7fffu + ((ul >> 16) & 1u);
    return h | (rl & 0xffff0000u);
}
__device__ __forceinline__ void split_bf16(float f, ushort_t& h, ushort_t& l) {
    unsigned p = pack_hl(f);
    h = (ushort_t)(p & 0xffffu);
    l = (ushort_t)(p >> 16);
}
__device__ __forceinline__ float upk_val(unsigned u) {
    return __uint_as_float(u << 16) + __uint_as_float(u & 0xffff0000u);
}

// deinterleave 8 packed uints -> bf16x8 hi, bf16x8 lo
__device__ __forceinline__ void unpack_frag(upk4 p0, upk4 p1, bf16x8& ah, bf16x8& al) {
    upk4 h, l;
#if __has_builtin(__builtin_amdgcn_perm)
    h.x = __builtin_amdgcn_perm(p0.y, p0.x, 0x05040100u);
    h.y = __builtin_amdgcn_perm(p0.w, p0.z, 0x05040100u);
    h.z = __builtin_amdgcn_perm(p1.y, p1.x, 0x05040100u);
    h.w = __builtin_amdgcn_perm(p1.w, p1.z, 0x05040100u);
    l.x = __builtin_amdgcn_perm(p0.y, p0.x, 0x07060302u);
    l.y = __builtin_amdgcn_perm(p0.w, p0.z, 0x07060302u);
    l.z = __builtin_amdgcn_perm(p1.y, p1.x, 0x07060302u);
    l.w = __builtin_amdgcn_perm(p1.w, p1.z, 0x07060302u);
#else
    h.x = (p0.x & 0xffffu) | (p0.y << 16);
    h.y = (p0.z & 0xffffu) | (p0.w << 16);
    h.z = (p1.x & 0xffffu) | (p1.y << 16);
    h.w = (p1.z & 0xffffu) | (p1.w << 16);
    l.x = (p0.x >> 16) | (p0.y & 0xffff0000u);
    l.y = (p0.z >> 16) | (p0.w & 0xffff0000u);
    l.z = (p1.x >> 16) | (p1.y & 0xffff0000u);
    l.w = (p1.z >> 16) | (p1.w & 0xffff0000u);
#endif
    ah = __builtin_bit_cast(bf16x8, h);
    al = __builtin_bit_cast(bf16x8, l);
}

// ---------------------------------------------------------------------------
// prep: [0,500) timestep-MLP LUT | [500,756) weight cvt+transpose |
//       [756,1268) x-input packed cvt | [1268,...) edge histogram
// ---------------------------------------------------------------------------
struct WDesc { const float* src; int K; int N; unsigned dst; };
struct WDescs { WDesc d[16]; };

#define PREP_LUT  500
#define PREP_CVTW 256
#define PREP_CVTX 512
#define PREP_HIST ((2 * NEDGE + 255) / 256)

__global__ __launch_bounds__(256) void prep_kernel(
        WDescs wd, ushort_t* __restrict__ WT,
        const float* __restrict__ teW1, const float* __restrict__ teb1,
        const float* __restrict__ teW2, const float* __restrict__ teb2,
        float* __restrict__ Tlut,
        const float* __restrict__ xu, const float* __restrict__ xi,
        unsigned* __restrict__ xup, unsigned* __restrict__ xip,
        const int* __restrict__ d0, const int* __restrict__ d1,
        int* __restrict__ cnt2) {
    __shared__ float sE[2][128];
    __shared__ float sH[2][128];
    int b = blockIdx.x;
    int tid = threadIdx.x;
    if (b < PREP_LUT) {
        int r = tid >> 7, j = tid & 127;
        int t = b * 2 + r;
        {
            int jj = j & 63;
            const float Lf = 9.210340371976184f;
            float p  = -Lf * (float)jj;
            float ae = p * 0.015625f;
            float freq = (float)exp((double)ae);
            float arg  = (float)t * freq;
            double a = (double)arg;
            sE[r][j] = (j < 64) ? (float)cos(a) : (float)sin(a);
        }
        __syncthreads();
        {
            float acc = teb1[j];
            for (int k = 0; k < 128; ++k) acc = fmaf(sE[r][k], teW1[k * 128 + j], acc);
            float s = 1.f / (1.f + expf(-acc));
            sH[r][j] = acc * s;
        }
        __syncthreads();
        {
            float acc = teb2[j];
            for (int k = 0; k < 128; ++k) acc = fmaf(sH[r][k], teW2[k * 128 + j], acc);
            Tlut[(size_t)t * 128 + j] = acc;
        }
    } else if (b < PREP_LUT + PREP_CVTW) {
        int g = (b - PREP_LUT) * 256 + tid;
        int gs = PREP_CVTW * 256;
#pragma unroll 1
        for (int i = 0; i < 16; ++i) {
            const WDesc w = wd.d[i];
            int sz = w.K * w.N;
            ushort_t* ph = WT + w.dst;
            ushort_t* pl = ph + sz;
            for (int e = g; e < sz; e += gs) {
                int k = e / w.N, n = e - k * w.N;
                ushort_t h, l;
                split_bf16(w.src[e], h, l);
                ph[(size_t)n * w.K + k] = h;
                pl[(size_t)n * w.K + k] = l;
            }
        }
    } else if (b < PREP_LUT + PREP_CVTW + PREP_CVTX) {
        int g = (b - PREP_LUT - PREP_CVTW) * 256 + tid;
        int gs = PREP_CVTX * 256;
        for (int i = g; i < NUSER * 64; i += gs) xup[i] = pack_hl(xu[i]);
        for (int i = g; i < NITEM * 32; i += gs) xip[i] = pack_hl(xi[i]);
    } else {
        int e = (b - PREP_LUT - PREP_CVTW - PREP_CVTX) * 256 + tid;
        if (e < NEDGE) atomicAdd(&cnt2[d0[e]], 1);
        else { e -= NEDGE; if (e < NEDGE) atomicAdd(&cnt2[NUSER + d1[e]], 1); }
    }
}

// ---------------------------------------------------------------------------
// MFMA GEMM (split-bf16, 3-pass):  Y = act( A@W1 [+ A2@W2] + bias [+ res] )
// A packed uint planes [M][K]; W transposed hi/lo ushort planes [NOUT][K].
// 4 waves/block, wave tile 64 x min(64,NOUT); no LDS; A regs prefetched 1 kt.
// OUTMODE bit0: fp32 Yf; bit1: packed Yp. RESMODE 2: += Tlut[tidx[m]].
// ---------------------------------------------------------------------------
#define ACT_NONE 0
#define ACT_RELU 1

struct MProb {
    const unsigned *A1p; int K1;
    const unsigned *A2p; int K2;
    const ushort_t *W1, *W2;            // hi plane; lo at +NOUT*K
    const float* bias; const float* res; const int* tidx;
    float* Yf; unsigned* Yp;
    int M; int nblk;
};

template<int NOUT, int ACT, bool DUAL, int RESMODE, int OUTMODE>
__global__ __launch_bounds__(256)
void mgemm_kernel(MProb q0, MProb q1) {
    constexpr int WN  = (NOUT >= 64) ? 64 : NOUT;
    constexpr int NWC = NOUT / WN;
    constexpr int NWR = 4 / NWC;
    constexpr int BM  = NWR * 64;
    constexpr int NF  = WN / 16;

    const bool firstp = (blockIdx.x < (unsigned)q0.nblk);
    const MProb& q = firstp ? q0 : q1;
    const int bid = firstp ? blockIdx.x : (blockIdx.x - q0.nblk);

    const int w    = threadIdx.x >> 6;
    const int lane = threadIdx.x & 63;
    const int wc   = w % NWC;
    const int wr   = w / NWC;
    const int mw   = bid * BM + wr * 64;
    const int nw   = wc * WN;
    const int lr   = lane & 15;
    const int lkg  = lane >> 4;

    f32x4 acc[4][NF];
#pragma unroll
    for (int i = 0; i < 4; ++i)
#pragma unroll
        for (int j = 0; j < NF; ++j) acc[i][j] = (f32x4)0.f;

    const int nkt1 = q.K1 / 32;
    const int nkt  = nkt1 + (DUAL ? q.K2 / 32 : 0);

    upk4 pa[4][2];
    auto loadA = [&](int kt) {
        const unsigned* Ap; int K, kk;
        if (!DUAL || kt < nkt1) { Ap = q.A1p; K = q.K1; kk = kt * 32; }
        else                    { Ap = q.A2p; K = q.K2; kk = (kt - nkt1) * 32; }
        const int kb = kk + lkg * 8;
#pragma unroll
        for (int mf = 0; mf < 4; ++mf) {
            int row = mw + mf * 16 + lr;
            if (row < q.M) {
                const upk4* p = reinterpret_cast<const upk4*>(Ap + (size_t)row * K + kb);
                pa[mf][0] = p[0]; pa[mf][1] = p[1];
            } else {
                pa[mf][0] = (upk4)0u; pa[mf][1] = (upk4)0u;
            }
        }
    };

    loadA(0);
#pragma unroll 1
    for (int kt = 0; kt < nkt; ++kt) {
        bf16x8 a_h[4], a_l[4];
#pragma unroll
        for (int mf = 0; mf < 4; ++mf) unpack_frag(pa[mf][0], pa[mf][1], a_h[mf], a_l[mf]);
        if (kt + 1 < nkt) loadA(kt + 1);          // prefetch next A tile

        const ushort_t* Wh; int K, kk;
        if (!DUAL || kt < nkt1) { Wh = q.W1; K = q.K1; kk = kt * 32; }
        else                    { Wh = q.W2; K = q.K2; kk = (kt - nkt1) * 32; }
        const ushort_t* Wl = Wh + (size_t)NOUT * K;
        const int kb = kk + lkg * 8;
        bf16x8 b_h[NF], b_l[NF];
#pragma unroll
        for (int nf = 0; nf < NF; ++nf) {
            int col = nw + nf * 16 + lr;
            b_h[nf] = *reinterpret_cast<const bf16x8*>(Wh + (size_t)col * K + kb);
            b_l[nf] = *reinterpret_cast<const bf16x8*>(Wl + (size_t)col * K + kb);
        }
#pragma unroll
        for (int mf = 0; mf < 4; ++mf)
#pragma unroll
            for (int nf = 0; nf < NF; ++nf) {
                acc[mf][nf] = __builtin_amdgcn_mfma_f32_16x16x32_bf16(a_h[mf], b_h[nf], acc[mf][nf], 0, 0, 0);
                acc[mf][nf] = __builtin_amdgcn_mfma_f32_16x16x32_bf16(a_h[mf], b_l[nf], acc[mf][nf], 0, 0, 0);
                acc[mf][nf] = __builtin_amdgcn_mfma_f32_16x16x32_bf16(a_l[mf], b_h[nf], acc[mf][nf], 0, 0, 0);
            }
    }

    // all reads complete before in-place epilogue stores (waves share rows)
    __syncthreads();

    float bcol[NF];
#pragma unroll
    for (int nf = 0; nf < NF; ++nf) bcol[nf] = q.bias[nw + nf * 16 + lr];

#pragma unroll
    for (int mf = 0; mf < 4; ++mf) {
#pragma unroll
        for (int r = 0; r < 4; ++r) {
            int row = mw + mf * 16 + lkg * 4 + r;
            if (row >= q.M) continue;
            const float* rp = nullptr;
            if (RESMODE == 2) { int tv = q.tidx[row]; rp = q.res + (size_t)tv * NOUT; }
#pragma unroll
            for (int nf = 0; nf < NF; ++nf) {
                int col = nw + nf * 16 + lr;
                float v = acc[mf][nf][r] + bcol[nf];
                if (RESMODE == 2) v += rp[col];
                if (ACT == ACT_RELU) v = fmaxf(v, 0.f);
                size_t o = (size_t)row * NOUT + col;
                if (OUTMODE & 1) q.Yf[o] = v;
                if (OUTMODE & 2) q.Yp[o] = pack_hl(v);
            }
        }
    }
}

// ---------------------------------------------------------------------------
// CSR scans (scan2 folded into scan3 via inline block-prefix)
// ---------------------------------------------------------------------------
#define SCAN_CHUNK 2048
#define GSCAN 25

__global__ __launch_bounds__(256) void scan1x2_kernel(const int* __restrict__ cnt2,
                                                      int* __restrict__ bsum2) {
    __shared__ int sdata[256];
    int p = blockIdx.x / GSCAN, b = blockIdx.x % GSCAN;
    const int* cnt = cnt2 + p * NUSER;
    int base = b * SCAN_CHUNK + threadIdx.x * 8;
    int s = 0;
#pragma unroll
    for (int j = 0; j < 8; ++j) { int i = base + j; if (i < NUSER) s += cnt[i]; }
    sdata[threadIdx.x] = s;
    __syncthreads();
    for (int st = 128; st > 0; st >>= 1) {
        if ((int)threadIdx.x < st) sdata[threadIdx.x] += sdata[threadIdx.x + st];
        __syncthreads();
    }
    if (threadIdx.x == 0) bsum2[p * 32 + b] = sdata[0];
}

__global__ __launch_bounds__(256) void scan3x2_kernel(const int* __restrict__ cnt2,
                                                      const int* __restrict__ bsum2,
                                                      int* __restrict__ off_ui,
                                                      int* __restrict__ off_iu,
                                                      int* __restrict__ wp2) {
    __shared__ int sth[256];
    int p = blockIdx.x / GSCAN, b = blockIdx.x % GSCAN;
    const int* cnt = cnt2 + p * NUSER;
    int* offs = p ? off_iu : off_ui;
    int* wp = wp2 + p * NUSER;
    int t = threadIdx.x;
    int boff = 0;
    for (int i = 0; i < b; ++i) boff += bsum2[p * 32 + i];
    int base = b * SCAN_CHUNK + t * 8;
    int loc[8];
    int s = 0;
#pragma unroll
    for (int j = 0; j < 8; ++j) {
        int i = base + j;
        int v = (i < NUSER) ? cnt[i] : 0;
        loc[j] = s; s += v;
    }
    sth[t] = s;
    __syncthreads();
    for (int st = 1; st < 256; st <<= 1) {
        int v = (t >= st) ? sth[t - st] : 0;
        __syncthreads();
        sth[t] += v;
        __syncthreads();
    }
    int exc = (t == 0) ? 0 : sth[t - 1];
#pragma unroll
    for (int j = 0; j < 8; ++j) {
        int i = base + j;
        if (i < NUSER) { int o = boff + exc + loc[j]; offs[i] = o; wp[i] = o; }
    }
    if (b == GSCAN - 1 && t == 255) offs[NUSER] = boff + sth[255];
}

__global__ __launch_bounds__(256) void fill2_kernel(const int* __restrict__ s0, const int* __restrict__ d0,
                                                    const int* __restrict__ s1, const int* __restrict__ d1,
                                                    int* __restrict__ wp2,
                                                    int* __restrict__ bkt0, int* __restrict__ bkt1, int E) {
    int e = blockIdx.x * 256 + threadIdx.x;
    if (e < E) {
        int d = d0[e];
        int p = atomicAdd(&wp2[d], 1);
        bkt0[p] = s0[e];
    } else {
        e -= E;
        if (e < E) {
            int d = d1[e];
            int p = atomicAdd(&wp2[NUSER + d], 1);
            bkt1[p] = s1[e];
        }
    }
}

// ---------------------------------------------------------------------------
// Paired segment-mean on packed planes: one wave per dst row; half-waves take
// alternate edges, uint4 (4 cols) per lane, 2 edges in flight per half.
// ---------------------------------------------------------------------------
struct GProb { const unsigned* Hp; const int* offs; const int* bkt; unsigned* Op; int N; };

__global__ __launch_bounds__(256)
void gather2p_kernel(GProb g0, GProb g1) {
    int gw = (blockIdx.x * 256 + threadIdx.x) >> 6;
    int lane = threadIdx.x & 63;
    const bool firstp = (gw < g0.N);
    const GProb& g = firstp ? g0 : g1;
    int row = firstp ? gw : gw - g0.N;
    if (row >= g.N) return;
    int beg = g.offs[row], end = g.offs[row + 1];
    int hf = lane >> 5, c = lane & 31;
    const upk4* __restrict__ base = reinterpret_cast<const upk4*>(g.Hp) + c;
    float s0 = 0.f, s1 = 0.f, s2 = 0.f, s3 = 0.f;
    auto accv = [&](upk4 v) {
        s0 += upk_val(v.x); s1 += upk_val(v.y);
        s2 += upk_val(v.z); s3 += upk_val(v.w);
    };
    int e = beg + hf;
    for (; e + 2 < end; e += 4) {
        int r0 = g.bkt[e], r1 = g.bkt[e + 2];
        upk4 v0 = base[(size_t)r0 * 32];
        upk4 v1 = base[(size_t)r1 * 32];
        accv(v0); accv(v1);
    }
    if (e < end) accv(base[(size_t)g.bkt[e] * 32]);
    s0 += __shfl_xor(s0, 32, 64);
    s1 += __shfl_xor(s1, 32, 64);
    s2 += __shfl_xor(s2, 32, 64);
    s3 += __shfl_xor(s3, 32, 64);
    if (hf == 0) {
        float d = (float)max(end - beg, 1);
        upk4 o;
        o.x = pack_hl(s0 / d); o.y = pack_hl(s1 / d);
        o.z = pack_hl(s2 / d); o.w = pack_hl(s3 / d);
        *reinterpret_cast<upk4*>(g.Op + (size_t)row * 128 + 4 * c) = o;
    }
}

// ---------------------------------------------------------------------------
extern "C" void kernel_launch(void* const* d_in, const int* in_sizes, int n_in,
                              void* d_out, int out_size, void* d_ws, size_t ws_size,
                              hipStream_t stream) {
    const float* x_user  = (const float*)d_in[0];
    const float* x_item  = (const float*)d_in[1];
    const int*   t_user  = (const int*)d_in[2];
    const int*   t_item  = (const int*)d_in[3];
    const int*   eui_src = (const int*)d_in[4];
    const int*   eui_dst = (const int*)d_in[5];
    const int*   eiu_src = (const int*)d_in[6];
    const int*   eiu_dst = (const int*)d_in[7];
    const float* te_W1 = (const float*)d_in[8];  const float* te_b1 = (const float*)d_in[9];
    const float* te_W2 = (const float*)d_in[10]; const float* te_b2 = (const float*)d_in[11];
    const float* proj_Wu = (const float*)d_in[12]; const float* proj_bu = (const float*)d_in[13];
    const float* proj_Wi = (const float*)d_in[14]; const float* proj_bi = (const float*)d_in[15];
    const float* sage_Wnbr  = (const float*)d_in[16];
    const float* sage_Wroot = (const float*)d_in[17];
    const float* sage_b     = (const float*)d_in[18];
    const float* mu_W1 = (const float*)d_in[19]; const float* mu_b1 = (const float*)d_in[20];
    const float* mu_W2 = (const float*)d_in[21]; const float* mu_b2 = (const float*)d_in[22];
    const float* mu_W3 = (const float*)d_in[23]; const float* mu_b3 = (const float*)d_in[24];
    const float* mi_W1 = (const float*)d_in[25]; const float* mi_b1 = (const float*)d_in[26];
    const float* mi_W2 = (const float*)d_in[27]; const float* mi_b2 = (const float*)d_in[28];
    const float* mi_W3 = (const float*)d_in[29]; const float* mi_b3 = (const float*)d_in[30];

    float* out_u = (float*)d_out;                  // [25000][64]
    float* out_i = out_u + (size_t)NIN * 64;       // [25000][32]

    // ---- workspace layout (packed uint planes) ----
    const size_t PL = (size_t)NUSER * DIMT;        // 6.4M elems
    float* Tlut = (float*)d_ws;                    // 1000*128 fp32
    unsigned* up = (unsigned*)(Tlut + NTVAL * 128);
    unsigned* Hp_u = up;                           // h_user packed
    unsigned* Hp_i = up + PL;                      // h_item packed
    unsigned* G0   = up + 2 * PL;                  // 2 planes: x / means / head temps
    unsigned* Gp_i = G0;
    unsigned* Gp_u = G0 + PL;
    ushort_t* WT   = (ushort_t*)(up + 4 * PL);

    WDescs wd;
    unsigned woff[16];
    unsigned off = 0; int wi = 0;
    auto addw = [&](const float* src, int K, int N) {
        wd.d[wi].src = src; wd.d[wi].K = K; wd.d[wi].N = N; wd.d[wi].dst = off;
        woff[wi] = off; off += 2u * K * N; ++wi;
    };
    addw(proj_Wu, 64, 128);                                    // 0
    addw(proj_Wi, 32, 128);                                    // 1
    for (int l = 0; l < 2; ++l)
        for (int e = 0; e < 2; ++e)
            addw(sage_Wnbr + (size_t)(l * 2 + e) * DIMT * DIMT, 128, 128);   // 2..5
    for (int l = 0; l < 2; ++l)
        for (int e = 0; e < 2; ++e)
            addw(sage_Wroot + (size_t)(l * 2 + e) * DIMT * DIMT, 128, 128);  // 6..9
    addw(mu_W1, 128, 256);                                     // 10
    addw(mu_W2, 256, 256);                                     // 11
    addw(mu_W3, 256, 64);                                      // 12
    addw(mi_W1, 128, 256);                                     // 13
    addw(mi_W2, 256, 256);                                     // 14
    addw(mi_W3, 256, 32);                                      // 15

    int* ip = (int*)(WT + off + (off & 1));
    int* cnt2   = ip;  ip += 2 * NUSER;
    int* wp2    = ip;  ip += 2 * NUSER;
    int* off_ui = ip;  ip += NUSER + 1;
    int* off_iu = ip;  ip += NUSER + 1;
    int* bkt_ui = ip;  ip += NEDGE;
    int* bkt_iu = ip;  ip += NEDGE;
    int* bsum2  = ip;  ip += 64;

    const int gEdges2 = (2 * NEDGE + 255) / 256;
    MProb qn = {}; qn.nblk = 0;

    // x packed planes live in the G region until proj is done
    unsigned* xu_p = G0;
    unsigned* xi_p = G0 + PL;

    // ---- prep: LUT + weight cvt + x cvt + histogram (one launch) ----
    hipMemsetAsync(cnt2, 0, 2 * NUSER * sizeof(int), stream);
    prep_kernel<<<PREP_LUT + PREP_CVTW + PREP_CVTX + PREP_HIST, 256, 0, stream>>>(
        wd, WT, te_W1, te_b1, te_W2, te_b2, Tlut,
        x_user, x_item, xu_p, xi_p, eui_dst, eiu_dst, cnt2);

    // ---- CSR build ----
    scan1x2_kernel<<<2 * GSCAN, 256, 0, stream>>>(cnt2, bsum2);
    scan3x2_kernel<<<2 * GSCAN, 256, 0, stream>>>(cnt2, bsum2, off_ui, off_iu, wp2);
    fill2_kernel<<<gEdges2, 256, 0, stream>>>(eui_src, eui_dst, eiu_src, eiu_dst, wp2, bkt_ui, bkt_iu, NEDGE);

    // ---- proj: h = x@W + b + Tlut[t] ----
    {
        MProb qu = {}; MProb qi = {};
        qu.A1p = xu_p; qu.K1 = 64;
        qu.W1 = WT + woff[0]; qu.bias = proj_bu; qu.res = Tlut; qu.tidx = t_user;
        qu.Yp = Hp_u; qu.M = NUSER; qu.nblk = (NUSER + 127) / 128;
        qi.A1p = xi_p; qi.K1 = 32;
        qi.W1 = WT + woff[1]; qi.bias = proj_bi; qi.res = Tlut; qi.tidx = t_item;
        qi.Yp = Hp_i; qi.M = NITEM; qi.nblk = (NITEM + 127) / 128;
        mgemm_kernel<128, ACT_NONE, false, 2, 2><<<qu.nblk + qi.nblk, 256, 0, stream>>>(qu, qi);
    }

    // ---- SAGE layers: paired gather, paired dual GEMM (in-place H) ----
    for (int l = 0; l < 2; ++l) {
        {
            GProb gi = { Hp_u, off_ui, bkt_ui, Gp_i, NITEM };
            GProb gu = { Hp_i, off_iu, bkt_iu, Gp_u, NUSER };
            gather2p_kernel<<<(NITEM + NUSER) * 64 / 256, 256, 0, stream>>>(gi, gu);
        }
        {
            MProb qi = {}; MProb qu = {};
            qi.A1p = Gp_i; qi.K1 = 128;
            qi.A2p = Hp_i; qi.K2 = 128;
            qi.W1 = WT + woff[2 + l * 2 + 0]; qi.W2 = WT + woff[6 + l * 2 + 0];
            qi.bias = sage_b + (size_t)(l * 2 + 0) * DIMT;
            qi.Yp = Hp_i; qi.M = NITEM; qi.nblk = (NITEM + 127) / 128;
            qu.A1p = Gp_u; qu.K1 = 128;
            qu.A2p = Hp_u; qu.K2 = 128;
            qu.W1 = WT + woff[2 + l * 2 + 1]; qu.W2 = WT + woff[6 + l * 2 + 1];
            qu.bias = sage_b + (size_t)(l * 2 + 1) * DIMT;
            qu.Yp = Hp_u; qu.M = NUSER; qu.nblk = (NUSER + 127) / 128;
            mgemm_kernel<128, ACT_RELU, true, 0, 2><<<qi.nblk + qu.nblk, 256, 0, stream>>>(qi, qu);
        }
    }

    // ---- MLP heads (rows 0..25000); temps reuse G region ----
    unsigned* Tp_u = G0;
    unsigned* Tp_i = G0 + PL;
    {
        MProb qu = {}; MProb qi = {};
        qu.A1p = Hp_u; qu.K1 = 128;
        qu.W1 = WT + woff[10]; qu.bias = mu_b1;
        qu.Yp = Tp_u; qu.M = NIN; qu.nblk = (NIN + 63) / 64;
        qi.A1p = Hp_i; qi.K1 = 128;
        qi.W1 = WT + woff[13]; qi.bias = mi_b1;
        qi.Yp = Tp_i; qi.M = NIN; qi.nblk = (NIN + 63) / 64;
        mgemm_kernel<256, ACT_RELU, false, 0, 2><<<qu.nblk + qi.nblk, 256, 0, stream>>>(qu, qi);
    }
    {
        MProb qu = {}; MProb qi = {};
        qu.A1p = Tp_u; qu.K1 = 256;
        qu.W1 = WT + woff[11]; qu.bias = mu_b2;
        qu.Yp = Tp_u; qu.M = NIN; qu.nblk = (NIN + 63) / 64;   // in-place (block-local rows)
        qi.A1p = Tp_i; qi.K1 = 256;
        qi.W1 = WT + woff[14]; qi.bias = mi_b2;
        qi.Yp = Tp_i; qi.M = NIN; qi.nblk = (NIN + 63) / 64;
        mgemm_kernel<256, ACT_RELU, false, 0, 2><<<qu.nblk + qi.nblk, 256, 0, stream>>>(qu, qi);
    }
    {
        MProb q = {};
        q.A1p = Tp_u; q.K1 = 256;
        q.W1 = WT + woff[12]; q.bias = mu_b3;
        q.Yf = out_u; q.M = NIN; q.nblk = (NIN + 255) / 256;
        mgemm_kernel<64, ACT_NONE, false, 0, 1><<<q.nblk, 256, 0, stream>>>(q, qn);
    }
    {
        MProb q = {};
        q.A1p = Tp_i; q.K1 = 256;
        q.W1 = WT + woff[15]; q.bias = mi_b3;
        q.Yf = out_i; q.M = NIN; q.nblk = (NIN + 255) / 256;
        mgemm_kernel<32, ACT_NONE, false, 0, 1><<<q.nblk, 256, 0, stream>>>(q, qn);
    }

    (void)in_sizes; (void)n_in; (void)out_size; (void)ws_size;
}

// Round 7
// 622.092 us; speedup vs baseline: 2.0091x; 1.0210x over previous
//
#include <hip/hip_runtime.h>
#include <math.h>

#define NEDGE 600000
#define NUSER 50000
#define NITEM 50000
#define DIMT  128
#define NIN   25000
#define NTVAL 1000

typedef unsigned short ushort_t;
typedef __attribute__((ext_vector_type(8))) short bf16x8;
typedef __attribute__((ext_vector_type(4))) float f32x4;
typedef __attribute__((ext_vector_type(4))) unsigned upk4;

// packed element: low16 = hi bf16, high16 = lo bf16 ; value = fh + fl
__device__ __forceinline__ unsigned pack_hl(float f) {
    unsigned u = __float_as_uint(f);
    unsigned r = u + 0x7fffu + ((u >> 16) & 1u);
    unsigned h = (r >> 16) & 0xffffu;
    float fh = __uint_as_float(h << 16);
    float fl = f - fh;
    unsigned ul = __float_as_uint(fl);
    unsigned rl = ul + 0x7fffu + ((ul >> 16) & 1u);
    return h | (rl & 0xffff0000u);
}
__device__ __forceinline__ void split_bf16(float f, ushort_t& h, ushort_t& l) {
    unsigned p = pack_hl(f);
    h = (ushort_t)(p & 0xffffu);
    l = (ushort_t)(p >> 16);
}
__device__ __forceinline__ float upk_val(unsigned u) {
    return __uint_as_float(u << 16) + __uint_as_float(u & 0xffff0000u);
}

// deinterleave 8 packed uints -> bf16x8 hi, bf16x8 lo
__device__ __forceinline__ void unpack_frag(upk4 p0, upk4 p1, bf16x8& ah, bf16x8& al) {
    upk4 h, l;
#if __has_builtin(__builtin_amdgcn_perm)
    h.x = __builtin_amdgcn_perm(p0.y, p0.x, 0x05040100u);
    h.y = __builtin_amdgcn_perm(p0.w, p0.z, 0x05040100u);
    h.z = __builtin_amdgcn_perm(p1.y, p1.x, 0x05040100u);
    h.w = __builtin_amdgcn_perm(p1.w, p1.z, 0x05040100u);
    l.x = __builtin_amdgcn_perm(p0.y, p0.x, 0x07060302u);
    l.y = __builtin_amdgcn_perm(p0.w, p0.z, 0x07060302u);
    l.z = __builtin_amdgcn_perm(p1.y, p1.x, 0x07060302u);
    l.w = __builtin_amdgcn_perm(p1.w, p1.z, 0x07060302u);
#else
    h.x = (p0.x & 0xffffu) | (p0.y << 16);
    h.y = (p0.z & 0xffffu) | (p0.w << 16);
    h.z = (p1.x & 0xffffu) | (p1.y << 16);
    h.w = (p1.z & 0xffffu) | (p1.w << 16);
    l.x = (p0.x >> 16) | (p0.y & 0xffff0000u);
    l.y = (p0.z >> 16) | (p0.w & 0xffff0000u);
    l.z = (p1.x >> 16) | (p1.y & 0xffff0000u);
    l.w = (p1.z >> 16) | (p1.w & 0xffff0000u);
#endif
    ah = __builtin_bit_cast(bf16x8, h);
    al = __builtin_bit_cast(bf16x8, l);
}

// ---------------------------------------------------------------------------
// prep: [0,500) timestep-MLP LUT | [500,756) weight cvt+transpose |
//       [756,1268) x-input packed cvt | [1268,1268+512) XCD-partitioned hist
// ---------------------------------------------------------------------------
struct WDesc { const float* src; int K; int N; unsigned dst; };
struct WDescs { WDesc d[16]; };

#define PREP_LUT  500
#define PREP_CVTW 256
#define PREP_CVTX 512
#define HIST_CH   64
#define PREP_HIST (8 * HIST_CH)
#define DRANGE    (NUSER / 8)   // 6250 dsts per XCD range

__global__ __launch_bounds__(256) void prep_kernel(
        WDescs wd, ushort_t* __restrict__ WT,
        const float* __restrict__ teW1, const float* __restrict__ teb1,
        const float* __restrict__ teW2, const float* __restrict__ teb2,
        float* __restrict__ Tlut,
        const float* __restrict__ xu, const float* __restrict__ xi,
        unsigned* __restrict__ xup, unsigned* __restrict__ xip,
        const int* __restrict__ d0, const int* __restrict__ d1,
        int* __restrict__ cnt2) {
    __shared__ float sE[2][128];
    __shared__ float sH[2][128];
    int b = blockIdx.x;
    int tid = threadIdx.x;
    if (b < PREP_LUT) {
        int r = tid >> 7, j = tid & 127;
        int t = b * 2 + r;
        {
            int jj = j & 63;
            const float Lf = 9.210340371976184f;
            float p  = -Lf * (float)jj;
            float ae = p * 0.015625f;
            float freq = (float)exp((double)ae);
            float arg  = (float)t * freq;
            double a = (double)arg;
            sE[r][j] = (j < 64) ? (float)cos(a) : (float)sin(a);
        }
        __syncthreads();
        {
            float acc = teb1[j];
            for (int k = 0; k < 128; ++k) acc = fmaf(sE[r][k], teW1[k * 128 + j], acc);
            float s = 1.f / (1.f + expf(-acc));
            sH[r][j] = acc * s;
        }
        __syncthreads();
        {
            float acc = teb2[j];
            for (int k = 0; k < 128; ++k) acc = fmaf(sH[r][k], teW2[k * 128 + j], acc);
            Tlut[(size_t)t * 128 + j] = acc;
        }
    } else if (b < PREP_LUT + PREP_CVTW) {
        int g = (b - PREP_LUT) * 256 + tid;
        int gs = PREP_CVTW * 256;
#pragma unroll 1
        for (int i = 0; i < 16; ++i) {
            const WDesc w = wd.d[i];
            int sz = w.K * w.N;
            ushort_t* ph = WT + w.dst;
            ushort_t* pl = ph + sz;
            for (int e = g; e < sz; e += gs) {
                int k = e / w.N, n = e - k * w.N;
                ushort_t h, l;
                split_bf16(w.src[e], h, l);
                ph[(size_t)n * w.K + k] = h;
                pl[(size_t)n * w.K + k] = l;
            }
        }
    } else if (b < PREP_LUT + PREP_CVTW + PREP_CVTX) {
        int g = (b - PREP_LUT - PREP_CVTW) * 256 + tid;
        int gs = PREP_CVTX * 256;
        for (int i = g; i < NUSER * 64; i += gs) xup[i] = pack_hl(xu[i]);
        for (int i = g; i < NITEM * 32; i += gs) xip[i] = pack_hl(xi[i]);
    } else {
        // XCD-range-partitioned histogram: block handles dst range [lo,hi)
        int hb = b - PREP_LUT - PREP_CVTW - PREP_CVTX;
        int r = hb & 7, c = hb >> 3;
        int lo = r * DRANGE, hi = lo + DRANGE;
        const int epb = (NEDGE + HIST_CH - 1) / HIST_CH;
        int e0 = c * epb, e1 = min(e0 + epb, NEDGE);
        for (int e = e0 + tid; e < e1; e += 256) {
            int d = d0[e];
            if (d >= lo && d < hi) atomicAdd(&cnt2[d], 1);
        }
        for (int e = e0 + tid; e < e1; e += 256) {
            int d = d1[e];
            if (d >= lo && d < hi) atomicAdd(&cnt2[NUSER + d], 1);
        }
    }
}

// ---------------------------------------------------------------------------
// MFMA GEMM (split-bf16, 3-pass):  Y = act( A@W1 [+ A2@W2] + bias [+ res] )
// A packed uint planes [M][K]; W transposed hi/lo ushort planes [NOUT][K].
// 4 waves/block, wave tile 64 x min(64,NOUT); no LDS; A regs prefetched 1 kt.
// OUTMODE bit0: fp32 Yf; bit1: packed Yp. RESMODE 2: += Tlut[tidx[m]].
// ---------------------------------------------------------------------------
#define ACT_NONE 0
#define ACT_RELU 1

struct MProb {
    const unsigned *A1p; int K1;
    const unsigned *A2p; int K2;
    const ushort_t *W1, *W2;            // hi plane; lo at +NOUT*K
    const float* bias; const float* res; const int* tidx;
    float* Yf; unsigned* Yp;
    int M; int nblk;
};

template<int NOUT, int ACT, bool DUAL, int RESMODE, int OUTMODE>
__global__ __launch_bounds__(256)
void mgemm_kernel(MProb q0, MProb q1) {
    constexpr int WN  = (NOUT >= 64) ? 64 : NOUT;
    constexpr int NWC = NOUT / WN;
    constexpr int NWR = 4 / NWC;
    constexpr int BM  = NWR * 64;
    constexpr int NF  = WN / 16;

    const bool firstp = (blockIdx.x < (unsigned)q0.nblk);
    const MProb& q = firstp ? q0 : q1;
    const int bid = firstp ? blockIdx.x : (blockIdx.x - q0.nblk);

    const int w    = threadIdx.x >> 6;
    const int lane = threadIdx.x & 63;
    const int wc   = w % NWC;
    const int wr   = w / NWC;
    const int mw   = bid * BM + wr * 64;
    const int nw   = wc * WN;
    const int lr   = lane & 15;
    const int lkg  = lane >> 4;

    f32x4 acc[4][NF];
#pragma unroll
    for (int i = 0; i < 4; ++i)
#pragma unroll
        for (int j = 0; j < NF; ++j) acc[i][j] = (f32x4)0.f;

    const int nkt1 = q.K1 / 32;
    const int nkt  = nkt1 + (DUAL ? q.K2 / 32 : 0);

    upk4 pa[4][2];
    auto loadA = [&](int kt) {
        const unsigned* Ap; int K, kk;
        if (!DUAL || kt < nkt1) { Ap = q.A1p; K = q.K1; kk = kt * 32; }
        else                    { Ap = q.A2p; K = q.K2; kk = (kt - nkt1) * 32; }
        const int kb = kk + lkg * 8;
#pragma unroll
        for (int mf = 0; mf < 4; ++mf) {
            int row = mw + mf * 16 + lr;
            if (row < q.M) {
                const upk4* p = reinterpret_cast<const upk4*>(Ap + (size_t)row * K + kb);
                pa[mf][0] = p[0]; pa[mf][1] = p[1];
            } else {
                pa[mf][0] = (upk4)0u; pa[mf][1] = (upk4)0u;
            }
        }
    };

    loadA(0);
#pragma unroll 1
    for (int kt = 0; kt < nkt; ++kt) {
        bf16x8 a_h[4], a_l[4];
#pragma unroll
        for (int mf = 0; mf < 4; ++mf) unpack_frag(pa[mf][0], pa[mf][1], a_h[mf], a_l[mf]);
        if (kt + 1 < nkt) loadA(kt + 1);          // prefetch next A tile

        const ushort_t* Wh; int K, kk;
        if (!DUAL || kt < nkt1) { Wh = q.W1; K = q.K1; kk = kt * 32; }
        else                    { Wh = q.W2; K = q.K2; kk = (kt - nkt1) * 32; }
        const ushort_t* Wl = Wh + (size_t)NOUT * K;
        const int kb = kk + lkg * 8;
        bf16x8 b_h[NF], b_l[NF];
#pragma unroll
        for (int nf = 0; nf < NF; ++nf) {
            int col = nw + nf * 16 + lr;
            b_h[nf] = *reinterpret_cast<const bf16x8*>(Wh + (size_t)col * K + kb);
            b_l[nf] = *reinterpret_cast<const bf16x8*>(Wl + (size_t)col * K + kb);
        }
#pragma unroll
        for (int mf = 0; mf < 4; ++mf)
#pragma unroll
            for (int nf = 0; nf < NF; ++nf) {
                acc[mf][nf] = __builtin_amdgcn_mfma_f32_16x16x32_bf16(a_h[mf], b_h[nf], acc[mf][nf], 0, 0, 0);
                acc[mf][nf] = __builtin_amdgcn_mfma_f32_16x16x32_bf16(a_h[mf], b_l[nf], acc[mf][nf], 0, 0, 0);
                acc[mf][nf] = __builtin_amdgcn_mfma_f32_16x16x32_bf16(a_l[mf], b_h[nf], acc[mf][nf], 0, 0, 0);
            }
    }

    // all reads complete before in-place epilogue stores (waves share rows)
    __syncthreads();

    float bcol[NF];
#pragma unroll
    for (int nf = 0; nf < NF; ++nf) bcol[nf] = q.bias[nw + nf * 16 + lr];

#pragma unroll
    for (int mf = 0; mf < 4; ++mf) {
#pragma unroll
        for (int r = 0; r < 4; ++r) {
            int row = mw + mf * 16 + lkg * 4 + r;
            if (row >= q.M) continue;
            const float* rp = nullptr;
            if (RESMODE == 2) { int tv = q.tidx[row]; rp = q.res + (size_t)tv * NOUT; }
#pragma unroll
            for (int nf = 0; nf < NF; ++nf) {
                int col = nw + nf * 16 + lr;
                float v = acc[mf][nf][r] + bcol[nf];
                if (RESMODE == 2) v += rp[col];
                if (ACT == ACT_RELU) v = fmaxf(v, 0.f);
                size_t o = (size_t)row * NOUT + col;
                if (OUTMODE & 1) q.Yf[o] = v;
                if (OUTMODE & 2) q.Yp[o] = pack_hl(v);
            }
        }
    }
}

// ---------------------------------------------------------------------------
// CSR scans (scan2 folded into scan3 via inline block-prefix)
// ---------------------------------------------------------------------------
#define SCAN_CHUNK 2048
#define GSCAN 25

__global__ __launch_bounds__(256) void scan1x2_kernel(const int* __restrict__ cnt2,
                                                      int* __restrict__ bsum2) {
    __shared__ int sdata[256];
    int p = blockIdx.x / GSCAN, b = blockIdx.x % GSCAN;
    const int* cnt = cnt2 + p * NUSER;
    int base = b * SCAN_CHUNK + threadIdx.x * 8;
    int s = 0;
#pragma unroll
    for (int j = 0; j < 8; ++j) { int i = base + j; if (i < NUSER) s += cnt[i]; }
    sdata[threadIdx.x] = s;
    __syncthreads();
    for (int st = 128; st > 0; st >>= 1) {
        if ((int)threadIdx.x < st) sdata[threadIdx.x] += sdata[threadIdx.x + st];
        __syncthreads();
    }
    if (threadIdx.x == 0) bsum2[p * 32 + b] = sdata[0];
}

__global__ __launch_bounds__(256) void scan3x2_kernel(const int* __restrict__ cnt2,
                                                      const int* __restrict__ bsum2,
                                                      int* __restrict__ off_ui,
                                                      int* __restrict__ off_iu,
                                                      int* __restrict__ wp2) {
    __shared__ int sth[256];
    int p = blockIdx.x / GSCAN, b = blockIdx.x % GSCAN;
    const int* cnt = cnt2 + p * NUSER;
    int* offs = p ? off_iu : off_ui;
    int* wp = wp2 + p * NUSER;
    int t = threadIdx.x;
    int boff = 0;
    for (int i = 0; i < b; ++i) boff += bsum2[p * 32 + i];
    int base = b * SCAN_CHUNK + t * 8;
    int loc[8];
    int s = 0;
#pragma unroll
    for (int j = 0; j < 8; ++j) {
        int i = base + j;
        int v = (i < NUSER) ? cnt[i] : 0;
        loc[j] = s; s += v;
    }
    sth[t] = s;
    __syncthreads();
    for (int st = 1; st < 256; st <<= 1) {
        int v = (t >= st) ? sth[t - st] : 0;
        __syncthreads();
        sth[t] += v;
        __syncthreads();
    }
    int exc = (t == 0) ? 0 : sth[t - 1];
#pragma unroll
    for (int j = 0; j < 8; ++j) {
        int i = base + j;
        if (i < NUSER) { int o = boff + exc + loc[j]; offs[i] = o; wp[i] = o; }
    }
    if (b == GSCAN - 1 && t == 255) offs[NUSER] = boff + sth[255];
}

// ---------------------------------------------------------------------------
// XCD-range-partitioned bucket fill: block (r=blockIdx&7) handles dst range
// [r*6250,(r+1)*6250) -> wp2 counter lines and bkt regions are single-XCD.
// bkt stored as ushort (src < 50000 < 65536).
// ---------------------------------------------------------------------------
#define FILL_CH 64

__global__ __launch_bounds__(256) void fill2x_kernel(
        const int* __restrict__ s0, const int* __restrict__ d0,
        const int* __restrict__ s1, const int* __restrict__ d1,
        int* __restrict__ wp2,
        ushort_t* __restrict__ bkt0, ushort_t* __restrict__ bkt1) {
    int r = blockIdx.x & 7, c = blockIdx.x >> 3;
    int lo = r * DRANGE, hi = lo + DRANGE;
    const int epb = (NEDGE + FILL_CH - 1) / FILL_CH;
    int e0 = c * epb, e1 = min(e0 + epb, NEDGE);
    for (int e = e0 + (int)threadIdx.x; e < e1; e += 256) {
        int d = d0[e];
        if (d >= lo && d < hi) { int p = atomicAdd(&wp2[d], 1); bkt0[p] = (ushort_t)s0[e]; }
    }
    for (int e = e0 + (int)threadIdx.x; e < e1; e += 256) {
        int d = d1[e];
        if (d >= lo && d < hi) { int p = atomicAdd(&wp2[NUSER + d], 1); bkt1[p] = (ushort_t)s1[e]; }
    }
}

// ---------------------------------------------------------------------------
// Paired segment-mean on packed planes: one wave per dst row; half-waves take
// alternate edges, uint4 (4 cols) per lane, 2 edges in flight per half.
// ---------------------------------------------------------------------------
struct GProb { const unsigned* Hp; const int* offs; const ushort_t* bkt; unsigned* Op; int N; };

__global__ __launch_bounds__(256)
void gather2p_kernel(GProb g0, GProb g1) {
    int gw = (blockIdx.x * 256 + threadIdx.x) >> 6;
    int lane = threadIdx.x & 63;
    const bool firstp = (gw < g0.N);
    const GProb& g = firstp ? g0 : g1;
    int row = firstp ? gw : gw - g0.N;
    if (row >= g.N) return;
    int beg = g.offs[row], end = g.offs[row + 1];
    int hf = lane >> 5, c = lane & 31;
    const upk4* __restrict__ base = reinterpret_cast<const upk4*>(g.Hp) + c;
    float s0 = 0.f, s1 = 0.f, s2 = 0.f, s3 = 0.f;
    auto accv = [&](upk4 v) {
        s0 += upk_val(v.x); s1 += upk_val(v.y);
        s2 += upk_val(v.z); s3 += upk_val(v.w);
    };
    int e = beg + hf;
    for (; e + 2 < end; e += 4) {
        int r0 = g.bkt[e], r1 = g.bkt[e + 2];
        upk4 v0 = base[(size_t)r0 * 32];
        upk4 v1 = base[(size_t)r1 * 32];
        accv(v0); accv(v1);
    }
    if (e < end) accv(base[(size_t)g.bkt[e] * 32]);
    s0 += __shfl_xor(s0, 32, 64);
    s1 += __shfl_xor(s1, 32, 64);
    s2 += __shfl_xor(s2, 32, 64);
    s3 += __shfl_xor(s3, 32, 64);
    if (hf == 0) {
        float d = (float)max(end - beg, 1);
        upk4 o;
        o.x = pack_hl(s0 / d); o.y = pack_hl(s1 / d);
        o.z = pack_hl(s2 / d); o.w = pack_hl(s3 / d);
        *reinterpret_cast<upk4*>(g.Op + (size_t)row * 128 + 4 * c) = o;
    }
}

// ---------------------------------------------------------------------------
extern "C" void kernel_launch(void* const* d_in, const int* in_sizes, int n_in,
                              void* d_out, int out_size, void* d_ws, size_t ws_size,
                              hipStream_t stream) {
    const float* x_user  = (const float*)d_in[0];
    const float* x_item  = (const float*)d_in[1];
    const int*   t_user  = (const int*)d_in[2];
    const int*   t_item  = (const int*)d_in[3];
    const int*   eui_src = (const int*)d_in[4];
    const int*   eui_dst = (const int*)d_in[5];
    const int*   eiu_src = (const int*)d_in[6];
    const int*   eiu_dst = (const int*)d_in[7];
    const float* te_W1 = (const float*)d_in[8];  const float* te_b1 = (const float*)d_in[9];
    const float* te_W2 = (const float*)d_in[10]; const float* te_b2 = (const float*)d_in[11];
    const float* proj_Wu = (const float*)d_in[12]; const float* proj_bu = (const float*)d_in[13];
    const float* proj_Wi = (const float*)d_in[14]; const float* proj_bi = (const float*)d_in[15];
    const float* sage_Wnbr  = (const float*)d_in[16];
    const float* sage_Wroot = (const float*)d_in[17];
    const float* sage_b     = (const float*)d_in[18];
    const float* mu_W1 = (const float*)d_in[19]; const float* mu_b1 = (const float*)d_in[20];
    const float* mu_W2 = (const float*)d_in[21]; const float* mu_b2 = (const float*)d_in[22];
    const float* mu_W3 = (const float*)d_in[23]; const float* mu_b3 = (const float*)d_in[24];
    const float* mi_W1 = (const float*)d_in[25]; const float* mi_b1 = (const float*)d_in[26];
    const float* mi_W2 = (const float*)d_in[27]; const float* mi_b2 = (const float*)d_in[28];
    const float* mi_W3 = (const float*)d_in[29]; const float* mi_b3 = (const float*)d_in[30];

    float* out_u = (float*)d_out;                  // [25000][64]
    float* out_i = out_u + (size_t)NIN * 64;       // [25000][32]

    // ---- workspace layout (packed uint planes) ----
    const size_t PL = (size_t)NUSER * DIMT;        // 6.4M elems
    float* Tlut = (float*)d_ws;                    // 1000*128 fp32
    unsigned* up = (unsigned*)(Tlut + NTVAL * 128);
    unsigned* Hp_u = up;                           // h_user packed
    unsigned* Hp_i = up + PL;                      // h_item packed
    unsigned* G0   = up + 2 * PL;                  // 2 planes: x / means / head temps
    unsigned* Gp_i = G0;
    unsigned* Gp_u = G0 + PL;
    ushort_t* WT   = (ushort_t*)(up + 4 * PL);

    WDescs wd;
    unsigned woff[16];
    unsigned off = 0; int wi = 0;
    auto addw = [&](const float* src, int K, int N) {
        wd.d[wi].src = src; wd.d[wi].K = K; wd.d[wi].N = N; wd.d[wi].dst = off;
        woff[wi] = off; off += 2u * K * N; ++wi;
    };
    addw(proj_Wu, 64, 128);                                    // 0
    addw(proj_Wi, 32, 128);                                    // 1
    for (int l = 0; l < 2; ++l)
        for (int e = 0; e < 2; ++e)
            addw(sage_Wnbr + (size_t)(l * 2 + e) * DIMT * DIMT, 128, 128);   // 2..5
    for (int l = 0; l < 2; ++l)
        for (int e = 0; e < 2; ++e)
            addw(sage_Wroot + (size_t)(l * 2 + e) * DIMT * DIMT, 128, 128);  // 6..9
    addw(mu_W1, 128, 256);                                     // 10
    addw(mu_W2, 256, 256);                                     // 11
    addw(mu_W3, 256, 64);                                      // 12
    addw(mi_W1, 128, 256);                                     // 13
    addw(mi_W2, 256, 256);                                     // 14
    addw(mi_W3, 256, 32);                                      // 15

    int* ip = (int*)(WT + off + (off & 1));
    int* cnt2   = ip;  ip += 2 * NUSER;
    int* wp2    = ip;  ip += 2 * NUSER;
    int* off_ui = ip;  ip += NUSER + 1;
    int* off_iu = ip;  ip += NUSER + 1;
    int* bsum2  = ip;  ip += 64;
    ushort_t* bkt_ui = (ushort_t*)ip;
    ushort_t* bkt_iu = bkt_ui + NEDGE;

    MProb qn = {}; qn.nblk = 0;

    // x packed planes live in the G region until proj is done
    unsigned* xu_p = G0;
    unsigned* xi_p = G0 + PL;

    // ---- prep: LUT + weight cvt + x cvt + partitioned histogram ----
    hipMemsetAsync(cnt2, 0, 2 * NUSER * sizeof(int), stream);
    prep_kernel<<<PREP_LUT + PREP_CVTW + PREP_CVTX + PREP_HIST, 256, 0, stream>>>(
        wd, WT, te_W1, te_b1, te_W2, te_b2, Tlut,
        x_user, x_item, xu_p, xi_p, eui_dst, eiu_dst, cnt2);

    // ---- CSR build ----
    scan1x2_kernel<<<2 * GSCAN, 256, 0, stream>>>(cnt2, bsum2);
    scan3x2_kernel<<<2 * GSCAN, 256, 0, stream>>>(cnt2, bsum2, off_ui, off_iu, wp2);
    fill2x_kernel<<<8 * FILL_CH, 256, 0, stream>>>(eui_src, eui_dst, eiu_src, eiu_dst,
                                                   wp2, bkt_ui, bkt_iu);

    // ---- proj: h = x@W + b + Tlut[t] ----
    {
        MProb qu = {}; MProb qi = {};
        qu.A1p = xu_p; qu.K1 = 64;
        qu.W1 = WT + woff[0]; qu.bias = proj_bu; qu.res = Tlut; qu.tidx = t_user;
        qu.Yp = Hp_u; qu.M = NUSER; qu.nblk = (NUSER + 127) / 128;
        qi.A1p = xi_p; qi.K1 = 32;
        qi.W1 = WT + woff[1]; qi.bias = proj_bi; qi.res = Tlut; qi.tidx = t_item;
        qi.Yp = Hp_i; qi.M = NITEM; qi.nblk = (NITEM + 127) / 128;
        mgemm_kernel<128, ACT_NONE, false, 2, 2><<<qu.nblk + qi.nblk, 256, 0, stream>>>(qu, qi);
    }

    // ---- SAGE layers: paired gather, paired dual GEMM (in-place H) ----
    for (int l = 0; l < 2; ++l) {
        {
            GProb gi = { Hp_u, off_ui, bkt_ui, Gp_i, NITEM };
            GProb gu = { Hp_i, off_iu, bkt_iu, Gp_u, NUSER };
            gather2p_kernel<<<(NITEM + NUSER) * 64 / 256, 256, 0, stream>>>(gi, gu);
        }
        {
            MProb qi = {}; MProb qu = {};
            qi.A1p = Gp_i; qi.K1 = 128;
            qi.A2p = Hp_i; qi.K2 = 128;
            qi.W1 = WT + woff[2 + l * 2 + 0]; qi.W2 = WT + woff[6 + l * 2 + 0];
            qi.bias = sage_b + (size_t)(l * 2 + 0) * DIMT;
            qi.Yp = Hp_i; qi.M = NITEM; qi.nblk = (NITEM + 127) / 128;
            qu.A1p = Gp_u; qu.K1 = 128;
            qu.A2p = Hp_u; qu.K2 = 128;
            qu.W1 = WT + woff[2 + l * 2 + 1]; qu.W2 = WT + woff[6 + l * 2 + 1];
            qu.bias = sage_b + (size_t)(l * 2 + 1) * DIMT;
            qu.Yp = Hp_u; qu.M = NUSER; qu.nblk = (NUSER + 127) / 128;
            mgemm_kernel<128, ACT_RELU, true, 0, 2><<<qi.nblk + qu.nblk, 256, 0, stream>>>(qi, qu);
        }
    }

    // ---- MLP heads (rows 0..25000); temps reuse G region ----
    unsigned* Tp_u = G0;
    unsigned* Tp_i = G0 + PL;
    {
        MProb qu = {}; MProb qi = {};
        qu.A1p = Hp_u; qu.K1 = 128;
        qu.W1 = WT + woff[10]; qu.bias = mu_b1;
        qu.Yp = Tp_u; qu.M = NIN; qu.nblk = (NIN + 63) / 64;
        qi.A1p = Hp_i; qi.K1 = 128;
        qi.W1 = WT + woff[13]; qi.bias = mi_b1;
        qi.Yp = Tp_i; qi.M = NIN; qi.nblk = (NIN + 63) / 64;
        mgemm_kernel<256, ACT_RELU, false, 0, 2><<<qu.nblk + qi.nblk, 256, 0, stream>>>(qu, qi);
    }
    {
        MProb qu = {}; MProb qi = {};
        qu.A1p = Tp_u; qu.K1 = 256;
        qu.W1 = WT + woff[11]; qu.bias = mu_b2;
        qu.Yp = Tp_u; qu.M = NIN; qu.nblk = (NIN + 63) / 64;   // in-place (block-local rows)
        qi.A1p = Tp_i; qi.K1 = 256;
        qi.W1 = WT + woff[14]; qi.bias = mi_b2;
        qi.Yp = Tp_i; qi.M = NIN; qi.nblk = (NIN + 63) / 64;
        mgemm_kernel<256, ACT_RELU, false, 0, 2><<<qu.nblk + qi.nblk, 256, 0, stream>>>(qu, qi);
    }
    {
        MProb q = {};
        q.A1p = Tp_u; q.K1 = 256;
        q.W1 = WT + woff[12]; q.bias = mu_b3;
        q.Yf = out_u; q.M = NIN; q.nblk = (NIN + 255) / 256;
        mgemm_kernel<64, ACT_NONE, false, 0, 1><<<q.nblk, 256, 0, stream>>>(q, qn);
    }
    {
        MProb q = {};
        q.A1p = Tp_i; q.K1 = 256;
        q.W1 = WT + woff[15]; q.bias = mi_b3;
        q.Yf = out_i; q.M = NIN; q.nblk = (NIN + 255) / 256;
        mgemm_kernel<32, ACT_NONE, false, 0, 1><<<q.nblk, 256, 0, stream>>>(q, qn);
    }

    (void)in_sizes; (void)n_in; (void)out_size; (void)ws_size;
}